// Round 14
// baseline (286.723 us; speedup 1.0000x reference)
//
#include <hip/hip_runtime.h>

#define HD 4      // heads
#define DD 128    // model dim
#define CC 32     // channels per head
#define SCAN_B 64
#define SCAN_T 256

// ---------------------------------------------------------------------------
// Precompute per-head weight column-sums and per-relation esum table.
// ---------------------------------------------------------------------------
__global__ __launch_bounds__(256) void prep_kernel(
    const float* __restrict__ Wq, const float* __restrict__ Wk,
    const float* __restrict__ We, const float* __restrict__ rel,
    float* __restrict__ Wqh, float* __restrict__ Wkh,
    float* __restrict__ esum, int R)
{
    __shared__ float WehS[2][DD][HD];   // 4 KB
    int tid = threadIdx.x;
    for (int i = tid; i < 2 * DD * HD; i += 256) {
        int l = i / (DD * HD);
        int d = (i / HD) % DD;
        int h = i % HD;
        const float* bq = Wq + ((size_t)l * DD + d) * DD + h * CC;
        const float* bk = Wk + ((size_t)l * DD + d) * DD + h * CC;
        const float* be = We + ((size_t)l * DD + d) * DD + h * CC;
        float sq = 0.f, sk = 0.f, se = 0.f;
        for (int c = 0; c < CC; ++c) { sq += bq[c]; sk += bk[c]; se += be[c]; }
        Wqh[i] = sq; Wkh[i] = sk; WehS[l][d][h] = se;
    }
    __syncthreads();
    for (int i = tid; i < 2 * R * HD; i += 256) {
        int l = i / (R * HD);
        int r = (i / HD) % R;
        int h = i % HD;
        const float* rp = rel + (size_t)r * DD;
        float a = 0.f;
        for (int d = 0; d < DD; ++d) a += rp[d] * WehS[l][d][h];
        esum[i] = a;
    }
}

// ---------------------------------------------------------------------------
// C[M x 128] = gather(A)[M x K] @ B[K x 128] (+bias). Tiled fp32 GEMM.
// Software-pipelined: next tile's global loads are issued right after the
// LDS store of the current tile, so HBM/L2 latency hides under the FMA burst.
// ---------------------------------------------------------------------------
__global__ __launch_bounds__(256) void gemm128(
    const float* __restrict__ A, const int* __restrict__ gather,
    const float* __restrict__ B, const float* __restrict__ bias,
    float* __restrict__ C, int M, int K)
{
    __shared__ float As[16][68];
    __shared__ float Bs[16][132];
    const int tid = threadIdx.x;
    const int row0 = blockIdx.x * 64;
    const int ty = tid >> 5, tx = tid & 31;
    float acc[8][4] = {};

    const int ar = tid >> 2;
    const int ak = (tid & 3) * 4;
    int arow = row0 + ar; if (arow >= M) arow = M - 1;
    const int grow = gather ? gather[arow] : arow;
    const float* Ap = A + (size_t)grow * K;
    const int bk = tid >> 4;
    const int bc = (tid & 15) * 8;

    // prologue: load tile 0
    float4 av = *(const float4*)(Ap + ak);
    float4 b0 = *(const float4*)(B + (size_t)bk * DD + bc);
    float4 b1 = *(const float4*)(B + (size_t)bk * DD + bc + 4);

    for (int k0 = 0; k0 < K; k0 += 16) {
        __syncthreads();                 // prev compute done reading LDS
        As[ak + 0][ar] = av.x; As[ak + 1][ar] = av.y;
        As[ak + 2][ar] = av.z; As[ak + 3][ar] = av.w;
        *(float4*)&Bs[bk][bc]     = b0;
        *(float4*)&Bs[bk][bc + 4] = b1;
        if (k0 + 16 < K) {               // issue next tile loads early
            av = *(const float4*)(Ap + k0 + 16 + ak);
            b0 = *(const float4*)(B + (size_t)(k0 + 16 + bk) * DD + bc);
            b1 = *(const float4*)(B + (size_t)(k0 + 16 + bk) * DD + bc + 4);
        }
        __syncthreads();                 // LDS tile ready
#pragma unroll
        for (int kk = 0; kk < 16; ++kk) {
            const float4 a0 = *(const float4*)&As[kk][ty * 8];
            const float4 a1 = *(const float4*)&As[kk][ty * 8 + 4];
            const float4 bv = *(const float4*)&Bs[kk][tx * 4];
            float a[8] = {a0.x, a0.y, a0.z, a0.w, a1.x, a1.y, a1.z, a1.w};
            float b[4] = {bv.x, bv.y, bv.z, bv.w};
#pragma unroll
            for (int i = 0; i < 8; ++i)
#pragma unroll
                for (int j = 0; j < 4; ++j) acc[i][j] += a[i] * b[j];
        }
    }
    float bv[4] = {0.f, 0.f, 0.f, 0.f};
    if (bias) {
        bv[0] = bias[tx * 4 + 0]; bv[1] = bias[tx * 4 + 1];
        bv[2] = bias[tx * 4 + 2]; bv[3] = bias[tx * 4 + 3];
    }
#pragma unroll
    for (int i = 0; i < 8; ++i) {
        int row = row0 + ty * 8 + i;
        if (row < M) {
            float4 r;
            r.x = acc[i][0] + bv[0]; r.y = acc[i][1] + bv[1];
            r.z = acc[i][2] + bv[2]; r.w = acc[i][3] + bv[3];
            *(float4*)&C[(size_t)row * DD + tx * 4] = r;
        }
    }
}

// ---------------------------------------------------------------------------
// Layer GEMM (K=128, no gather) with FUSED qs/ks computation; same
// software-pipelined staging (qk partials taken before register overwrite).
// ---------------------------------------------------------------------------
__global__ __launch_bounds__(256) void gemm_v_qk(
    const float* __restrict__ A, const float* __restrict__ B,
    const float* __restrict__ Wqh, const float* __restrict__ Wkh,
    float* __restrict__ C, float* __restrict__ qs, float* __restrict__ ks,
    int M)
{
    __shared__ float As[16][68];
    __shared__ float Bs[16][132];
    __shared__ float wqS[DD * HD], wkS[DD * HD];
    const int tid = threadIdx.x;
    const int row0 = blockIdx.x * 64;
    const int ty = tid >> 5, tx = tid & 31;
    float acc[8][4] = {};
    float qp[4] = {}, kp[4] = {};

    for (int i = tid; i < DD * HD; i += 256) { wqS[i] = Wqh[i]; wkS[i] = Wkh[i]; }

    const int ar = tid >> 2;
    const int ak = (tid & 3) * 4;
    int arow = row0 + ar; if (arow >= M) arow = M - 1;
    const float* Ap = A + (size_t)arow * DD;
    const int bk = tid >> 4;
    const int bc = (tid & 15) * 8;

    float4 av = *(const float4*)(Ap + ak);
    float4 b0 = *(const float4*)(B + (size_t)bk * DD + bc);
    float4 b1 = *(const float4*)(B + (size_t)bk * DD + bc + 4);

    for (int k0 = 0; k0 < DD; k0 += 16) {
        __syncthreads();
        As[ak + 0][ar] = av.x; As[ak + 1][ar] = av.y;
        As[ak + 2][ar] = av.z; As[ak + 3][ar] = av.w;
        *(float4*)&Bs[bk][bc]     = b0;
        *(float4*)&Bs[bk][bc + 4] = b1;
        // fused qk partials from current tile registers (before overwrite)
        {
            float axr[4] = {av.x, av.y, av.z, av.w};
#pragma unroll
            for (int i = 0; i < 4; ++i) {
                int d = k0 + ak + i;
                float xv = axr[i];
#pragma unroll
                for (int h = 0; h < 4; ++h) {
                    qp[h] += xv * wqS[d * HD + h];
                    kp[h] += xv * wkS[d * HD + h];
                }
            }
        }
        if (k0 + 16 < DD) {              // issue next tile loads early
            av = *(const float4*)(Ap + k0 + 16 + ak);
            b0 = *(const float4*)(B + (size_t)(k0 + 16 + bk) * DD + bc);
            b1 = *(const float4*)(B + (size_t)(k0 + 16 + bk) * DD + bc + 4);
        }
        __syncthreads();
#pragma unroll
        for (int kk = 0; kk < 16; ++kk) {
            const float4 a0 = *(const float4*)&As[kk][ty * 8];
            const float4 a1 = *(const float4*)&As[kk][ty * 8 + 4];
            const float4 bv = *(const float4*)&Bs[kk][tx * 4];
            float a[8] = {a0.x, a0.y, a0.z, a0.w, a1.x, a1.y, a1.z, a1.w};
            float b[4] = {bv.x, bv.y, bv.z, bv.w};
#pragma unroll
            for (int i = 0; i < 8; ++i)
#pragma unroll
                for (int j = 0; j < 4; ++j) acc[i][j] += a[i] * b[j];
        }
    }

    // reduce qp/kp across the 4 consecutive lanes sharing row ar
#pragma unroll
    for (int off = 1; off < 4; off <<= 1) {
#pragma unroll
        for (int h = 0; h < 4; ++h) {
            qp[h] += __shfl_xor(qp[h], off, 64);
            kp[h] += __shfl_xor(kp[h], off, 64);
        }
    }
    if ((tid & 3) == 0) {
        int row = row0 + ar;
        if (row < M) {
            *(float4*)&qs[(size_t)row * HD] = make_float4(qp[0], qp[1], qp[2], qp[3]);
            *(float4*)&ks[(size_t)row * HD] = make_float4(kp[0], kp[1], kp[2], kp[3]);
        }
    }

#pragma unroll
    for (int i = 0; i < 8; ++i) {
        int row = row0 + ty * 8 + i;
        if (row < M) {
            float4 r;
            r.x = acc[i][0]; r.y = acc[i][1]; r.z = acc[i][2]; r.w = acc[i][3];
            *(float4*)&C[(size_t)row * DD + tx * 4] = r;
        }
    }
}

// ---------------------------------------------------------------------------
// CSR build: histogram + hierarchical 3-kernel scan + packed scatter.
// ---------------------------------------------------------------------------
__global__ __launch_bounds__(256) void csr_count(
    const int* __restrict__ dstv, int* __restrict__ deg, int E)
{
    int t = blockIdx.x * 256 + threadIdx.x;
    if (t < E) atomicAdd(&deg[dstv[t]], 1);
}

__global__ __launch_bounds__(SCAN_T) void scan_partial(
    const int* __restrict__ deg, int* __restrict__ blksum, int N)
{
    __shared__ int red[SCAN_T];
    int chunk = (N + SCAN_B - 1) / SCAN_B;
    int b0 = blockIdx.x * chunk;
    int e0 = b0 + chunk; if (e0 > N) e0 = N;
    int s = 0;
    for (int i = b0 + threadIdx.x; i < e0; i += SCAN_T) s += deg[i];
    red[threadIdx.x] = s;
    __syncthreads();
    for (int off = SCAN_T / 2; off > 0; off >>= 1) {
        if (threadIdx.x < off) red[threadIdx.x] += red[threadIdx.x + off];
        __syncthreads();
    }
    if (threadIdx.x == 0) blksum[blockIdx.x] = red[0];
}

__global__ __launch_bounds__(64) void scan_blk(
    const int* __restrict__ blksum, int* __restrict__ blkoff)
{
    if (threadIdx.x == 0) {
        int acc = 0;
        for (int i = 0; i < SCAN_B; ++i) { blkoff[i] = acc; acc += blksum[i]; }
        blkoff[SCAN_B] = acc;
    }
}

__global__ __launch_bounds__(SCAN_T) void scan_final(
    const int* __restrict__ deg, const int* __restrict__ blkoff,
    int* __restrict__ row_ptr, int N)
{
    __shared__ int tsum[SCAN_T];
    int tid = threadIdx.x;
    int chunk = (N + SCAN_B - 1) / SCAN_B;
    int b0 = blockIdx.x * chunk;
    int e0 = b0 + chunk; if (e0 > N) e0 = N;
    int tchunk = (chunk + SCAN_T - 1) / SCAN_T;
    int tb = b0 + tid * tchunk;
    int te = tb + tchunk; if (te > e0) te = e0;
    int s = 0;
    for (int i = tb; i < te; ++i) s += deg[i];
    tsum[tid] = s;
    __syncthreads();
    for (int off = 1; off < SCAN_T; off <<= 1) {
        int v = (tid >= off) ? tsum[tid - off] : 0;
        __syncthreads();
        tsum[tid] += v;
        __syncthreads();
    }
    int base = blkoff[blockIdx.x] + ((tid == 0) ? 0 : tsum[tid - 1]);
    for (int i = tb; i < te; ++i) { row_ptr[i] = base; base += deg[i]; }
    if (blockIdx.x == SCAN_B - 1 && tid == SCAN_T - 1) row_ptr[N] = blkoff[SCAN_B];
}

__global__ __launch_bounds__(256) void csr_scatter(
    const int* __restrict__ srcv, const int* __restrict__ dstv,
    const int* __restrict__ etype, const float* __restrict__ ew,
    const int* __restrict__ row_ptr, int* __restrict__ cursor,
    int4* __restrict__ c_pack, int E)
{
    int e = blockIdx.x * 256 + threadIdx.x;
    if (e >= E) return;
    int d = dstv[e];
    int p = row_ptr[d] + atomicAdd(&cursor[d], 1);
    c_pack[p] = make_int4(srcv[e], etype[e], __float_as_int(ew[e]), 0);
}

// ---------------------------------------------------------------------------
// Fused per-layer edge+softmax+aggregate+epilogue. One wave per dst node.
// Lane l owns channels {2l, 2l+1}; head h = l>>4; per-lane single-head alpha.
// ---------------------------------------------------------------------------
__global__ __launch_bounds__(256) void fused_conv(
    const int* __restrict__ row_ptr, const int4* __restrict__ c_pack,
    const float* __restrict__ qs, const float* __restrict__ ks,
    const float* __restrict__ esum, const float* __restrict__ gate,
    const float* __restrict__ v, const float* __restrict__ bias,
    float* __restrict__ out, int N, int do_elu)
{
    int gw = (blockIdx.x * 256 + threadIdx.x) >> 6;   // global wave id = node
    int lane = threadIdx.x & 63;
    if (gw >= N) return;
    const int n = gw;
    const int beg = row_ptr[n], end = row_ptr[n + 1];
    const int c0 = lane * 2;
    const int h = lane >> 4;          // head of channels 2l, 2l+1
    const float qh = qs[(size_t)n * HD + h];
    const float gh = gate[h];
    const float sc = 0.17677669529663687f;   // 1/sqrt(32)

    float num0 = 0.f, num1 = 0.f, den = 0.f;

    int j = beg;
    int4 p;
    if (j < end) p = c_pack[j];
    while (j < end) {
        int4 cur = p;
        ++j;
        if (j < end) p = c_pack[j];           // prefetch next record
        int s = cur.x, r = cur.y;
        float w = __int_as_float(cur.z);
        float kh = ks[(size_t)s * HD + h];
        float eh = esum[(size_t)r * HD + h];
        float2 vv = *(const float2*)&v[(size_t)s * DD + c0];
        float a = (qh + kh + eh) * sc + gh * w;
        a = a > 0.f ? a : 0.2f * a;           // leaky_relu(0.2)
        float e = __expf(a);
        den += e;
        num0 = fmaf(e, vv.x, num0);
        num1 = fmaf(e, vv.y, num1);
    }

    float inv = 1.f / (den + 1e-16f);
    float r0 = num0 * inv + bias[c0];
    float r1 = num1 * inv + bias[c0 + 1];
    if (do_elu) {
        r0 = r0 > 0.f ? r0 : expm1f(r0);
        r1 = r1 > 0.f ? r1 : expm1f(r1);
    }
    *(float2*)&out[(size_t)n * DD + c0] = make_float2(r0, r1);
}

// ---------------------------------------------------------------------------
extern "C" void kernel_launch(void* const* d_in, const int* in_sizes, int n_in,
                              void* d_out, int out_size, void* d_ws, size_t ws_size,
                              hipStream_t stream)
{
    const int*   entity = (const int*)d_in[0];
    const int*   eidx   = (const int*)d_in[1];
    const int*   etype  = (const int*)d_in[2];
    const float* ew     = (const float*)d_in[3];
    const float* ent    = (const float*)d_in[4];
    const float* pw     = (const float*)d_in[5];
    const float* pb     = (const float*)d_in[6];
    const float* rel    = (const float*)d_in[7];
    const float* Wq     = (const float*)d_in[8];
    const float* Wk     = (const float*)d_in[9];
    const float* Wv     = (const float*)d_in[10];
    const float* We     = (const float*)d_in[11];
    const float* gate   = (const float*)d_in[12];
    const float* cb     = (const float*)d_in[13];

    const int N = in_sizes[0];
    const int E = in_sizes[2];
    const int F = in_sizes[4] / N;     // 256
    const int R = in_sizes[7] / DD;    // 200

    const int* srcv = eidx;
    const int* dstv = eidx + E;

    float* ws = (float*)d_ws;
    size_t o = 0;
    float* xbuf    = ws + o; o += (size_t)N * DD;
    float* vbuf    = ws + o; o += (size_t)N * DD;
    float* qs      = ws + o; o += (size_t)N * HD;
    float* ks      = ws + o; o += (size_t)N * HD;
    float* Wqh     = ws + o; o += 2 * DD * HD;
    float* Wkh     = ws + o; o += 2 * DD * HD;
    float* esum    = ws + o; o += (size_t)2 * R * HD;
    int*   deg     = (int*)(ws + o); o += N;
    int*   cursor  = (int*)(ws + o); o += N;
    int*   row_ptr = (int*)(ws + o); o += (size_t)N + 1;
    int*   blksum  = (int*)(ws + o); o += SCAN_B;
    int*   blkoff  = (int*)(ws + o); o += SCAN_B + 1;
    o = (o + 3) & ~(size_t)3;                       // 16B-align c_pack
    int4*  c_pack  = (int4*)(ws + o); o += (size_t)E * 4;

    prep_kernel<<<1, 256, 0, stream>>>(Wq, Wk, We, rel, Wqh, Wkh, esum, R);

    // CSR build (layer-independent, built once)
    hipMemsetAsync(deg, 0, (size_t)2 * N * sizeof(int), stream);  // deg + cursor
    csr_count<<<(E + 255) / 256, 256, 0, stream>>>(dstv, deg, E);
    scan_partial<<<SCAN_B, SCAN_T, 0, stream>>>(deg, blksum, N);
    scan_blk<<<1, 64, 0, stream>>>(blksum, blkoff);
    scan_final<<<SCAN_B, SCAN_T, 0, stream>>>(deg, blkoff, row_ptr, N);
    csr_scatter<<<(E + 255) / 256, 256, 0, stream>>>(
        srcv, dstv, etype, ew, row_ptr, cursor, c_pack, E);

    const int gblk = (N + 63) / 64;
    // x0 = ent_table[entity] @ proj_w + proj_b
    gemm128<<<gblk, 256, 0, stream>>>(ent, entity, pw, pb, xbuf, N, F);

    const int fblk = (N + 3) / 4;     // one 64-lane wave per node
    for (int l = 0; l < 2; ++l) {
        gemm_v_qk<<<gblk, 256, 0, stream>>>(
            xbuf, Wv + (size_t)l * DD * DD, Wqh + l * DD * HD, Wkh + l * DD * HD,
            vbuf, qs, ks, N);
        fused_conv<<<fblk, 256, 0, stream>>>(
            row_ptr, c_pack, qs, ks, esum + (size_t)l * R * HD,
            gate + l * HD, vbuf, cb + l * DD,
            (l == 0) ? xbuf : (float*)d_out, N, (l == 0) ? 1 : 0);
    }
}

// Round 15
// 265.652 us; speedup vs baseline: 1.0793x; 1.0793x over previous
//
#include <hip/hip_runtime.h>

#define HD 4      // heads
#define DD 128    // model dim
#define CC 32     // channels per head
#define SCAN_B 64
#define SCAN_T 256

typedef float  f32x4  __attribute__((ext_vector_type(4)));
typedef short  short8v __attribute__((ext_vector_type(8)));

__device__ __forceinline__ unsigned short f2bf(float x) {
    unsigned u = __float_as_uint(x);
    return (unsigned short)((u + 0x7FFFu + ((u >> 16) & 1u)) >> 16);
}
__device__ __forceinline__ float bf2f(unsigned short h) {
    return __uint_as_float((unsigned)h << 16);
}

// ---------------------------------------------------------------------------
// Precompute per-head weight column-sums and per-relation esum table.
// ---------------------------------------------------------------------------
__global__ __launch_bounds__(256) void prep_kernel(
    const float* __restrict__ Wq, const float* __restrict__ Wk,
    const float* __restrict__ We, const float* __restrict__ rel,
    float* __restrict__ Wqh, float* __restrict__ Wkh,
    float* __restrict__ esum, int R)
{
    __shared__ float WehS[2][DD][HD];   // 4 KB
    int tid = threadIdx.x;
    for (int i = tid; i < 2 * DD * HD; i += 256) {
        int l = i / (DD * HD);
        int d = (i / HD) % DD;
        int h = i % HD;
        const float* bq = Wq + ((size_t)l * DD + d) * DD + h * CC;
        const float* bk = Wk + ((size_t)l * DD + d) * DD + h * CC;
        const float* be = We + ((size_t)l * DD + d) * DD + h * CC;
        float sq = 0.f, sk = 0.f, se = 0.f;
        for (int c = 0; c < CC; ++c) { sq += bq[c]; sk += bk[c]; se += be[c]; }
        Wqh[i] = sq; Wkh[i] = sk; WehS[l][d][h] = se;
    }
    __syncthreads();
    for (int i = tid; i < 2 * R * HD; i += 256) {
        int l = i / (R * HD);
        int r = (i / HD) % R;
        int h = i % HD;
        const float* rp = rel + (size_t)r * DD;
        float a = 0.f;
        for (int d = 0; d < DD; ++d) a += rp[d] * WehS[l][d][h];
        esum[i] = a;
    }
}

// ---------------------------------------------------------------------------
// Split weights into transposed bf16 hi/lo tables:
//   btp_[col][k] for proj_w[256][128]; btv_[(l*128+col)][k] for Wv[l][128][128]
// ---------------------------------------------------------------------------
__global__ __launch_bounds__(256) void prep_bt(
    const float* __restrict__ pw, const float* __restrict__ Wv,
    unsigned short* __restrict__ btp_h, unsigned short* __restrict__ btp_l,
    unsigned short* __restrict__ btv_h, unsigned short* __restrict__ btv_l)
{
    int t = blockIdx.x * 256 + threadIdx.x;
    if (t < 128 * 256) {
        int col = t >> 8, k = t & 255;
        float v = pw[(size_t)k * DD + col];
        unsigned short h = f2bf(v);
        btp_h[(size_t)col * 256 + k] = h;
        btp_l[(size_t)col * 256 + k] = f2bf(v - bf2f(h));
    } else if (t < 128 * 256 + 2 * DD * DD) {
        int u = t - 128 * 256;
        int l = u >> 14;
        int r = u & 16383;
        int col = r >> 7, k = r & 127;
        float v = Wv[((size_t)l * DD + k) * DD + col];
        unsigned short h = f2bf(v);
        btv_h[((size_t)l * DD + col) * DD + k] = h;
        btv_l[((size_t)l * DD + col) * DD + k] = f2bf(v - bf2f(h));
    }
}

// ---------------------------------------------------------------------------
// Split-bf16 MFMA GEMM: C[M x 128] = gather(A)[M x K] @ B[K x 128] (+bias),
// 3-pass hi/lo (AhBh + AhBl + AlBh). Block: 64 rows x 128 cols, 4 waves;
// wave w owns rows w*16..w*16+16, 8 col-tiles of 16. Optional fused qs/ks.
// Frag layouts (m89/m91): A row=lane&15,k=(lane>>4)*8+j; B col=lane&15;
// D col=lane&15,row=(lane>>4)*4+i.
// ---------------------------------------------------------------------------
__global__ __launch_bounds__(256) void gemm_mfma(
    const float* __restrict__ A, const int* __restrict__ gather,
    const unsigned short* __restrict__ bth, const unsigned short* __restrict__ btl,
    const float* __restrict__ bias,
    const float* __restrict__ Wqh, const float* __restrict__ Wkh,
    float* __restrict__ C, float* __restrict__ qs, float* __restrict__ ks,
    int M, int K)
{
    __shared__ unsigned short Ah[64][40], Al[64][40];     // 80B row stride (16B-mult)
    __shared__ unsigned short Bh[128][40], Bl[128][40];
    __shared__ float wq[DD * HD], wk[DD * HD];

    const int tid = threadIdx.x;
    const int wave = tid >> 6, lane = tid & 63;
    const int row0 = blockIdx.x * 64;

    if (qs) {
        for (int i = tid; i < DD * HD; i += 256) { wq[i] = Wqh[i]; wk[i] = Wkh[i]; }
    }

    // A staging: thread handles rows sr and sr+32, k-chunk sc..sc+4
    const int sr = tid >> 3;           // 0..31
    const int sc = (tid & 7) * 4;      // 0,4,...,28
    int r1 = row0 + sr;      if (r1 >= M) r1 = M - 1;
    int r2 = row0 + sr + 32; if (r2 >= M) r2 = M - 1;
    const int g1 = gather ? gather[r1] : r1;
    const int g2 = gather ? gather[r2] : r2;
    const float* Ap0 = A + (size_t)g1 * K;
    const float* Ap1 = A + (size_t)g2 * K;

    // B staging: thread handles col bcol, k-half bseg
    const int bcol = tid & 127;
    const int bseg = (tid >> 7) * 16;  // 0 or 16
    const unsigned short* bhp = bth + (size_t)bcol * K;
    const unsigned short* blp = btl + (size_t)bcol * K;

    // MFMA fragment addressing
    const int fr = lane & 15, fg = lane >> 4;

    f32x4 acc[8] = {};
    float qp0[4] = {}, qp1[4] = {}, kp0[4] = {}, kp1[4] = {};

    for (int k0 = 0; k0 < K; k0 += 32) {
        float4 a0 = *(const float4*)(Ap0 + k0 + sc);
        float4 a1 = *(const float4*)(Ap1 + k0 + sc);
        short8v bh0 = *(const short8v*)(bhp + k0 + bseg);
        short8v bh1 = *(const short8v*)(bhp + k0 + bseg + 8);
        short8v bl0 = *(const short8v*)(blp + k0 + bseg);
        short8v bl1 = *(const short8v*)(blp + k0 + bseg + 8);
        __syncthreads();                     // prev MFMA reads done
        {
            short4 h0, l0, h1, l1;
            unsigned short h;
            h = f2bf(a0.x); h0.x = (short)h; l0.x = (short)f2bf(a0.x - bf2f(h));
            h = f2bf(a0.y); h0.y = (short)h; l0.y = (short)f2bf(a0.y - bf2f(h));
            h = f2bf(a0.z); h0.z = (short)h; l0.z = (short)f2bf(a0.z - bf2f(h));
            h = f2bf(a0.w); h0.w = (short)h; l0.w = (short)f2bf(a0.w - bf2f(h));
            h = f2bf(a1.x); h1.x = (short)h; l1.x = (short)f2bf(a1.x - bf2f(h));
            h = f2bf(a1.y); h1.y = (short)h; l1.y = (short)f2bf(a1.y - bf2f(h));
            h = f2bf(a1.z); h1.z = (short)h; l1.z = (short)f2bf(a1.z - bf2f(h));
            h = f2bf(a1.w); h1.w = (short)h; l1.w = (short)f2bf(a1.w - bf2f(h));
            *(short4*)&Ah[sr][sc]      = h0; *(short4*)&Al[sr][sc]      = l0;
            *(short4*)&Ah[sr + 32][sc] = h1; *(short4*)&Al[sr + 32][sc] = l1;
        }
        *(short8v*)&Bh[bcol][bseg]     = bh0;
        *(short8v*)&Bh[bcol][bseg + 8] = bh1;
        *(short8v*)&Bl[bcol][bseg]     = bl0;
        *(short8v*)&Bl[bcol][bseg + 8] = bl1;
        if (qs) {   // fused qk partials from exact fp32 A values
            const float av0[4] = {a0.x, a0.y, a0.z, a0.w};
            const float av1[4] = {a1.x, a1.y, a1.z, a1.w};
#pragma unroll
            for (int i = 0; i < 4; ++i) {
                float4 qw = *(const float4*)&wq[(k0 + sc + i) * HD];
                float4 kw = *(const float4*)&wk[(k0 + sc + i) * HD];
                qp0[0] += av0[i] * qw.x; qp0[1] += av0[i] * qw.y;
                qp0[2] += av0[i] * qw.z; qp0[3] += av0[i] * qw.w;
                qp1[0] += av1[i] * qw.x; qp1[1] += av1[i] * qw.y;
                qp1[2] += av1[i] * qw.z; qp1[3] += av1[i] * qw.w;
                kp0[0] += av0[i] * kw.x; kp0[1] += av0[i] * kw.y;
                kp0[2] += av0[i] * kw.z; kp0[3] += av0[i] * kw.w;
                kp1[0] += av1[i] * kw.x; kp1[1] += av1[i] * kw.y;
                kp1[2] += av1[i] * kw.z; kp1[3] += av1[i] * kw.w;
            }
        }
        __syncthreads();                     // tile staged
        short8v ah = *(const short8v*)&Ah[wave * 16 + fr][fg * 8];
        short8v al = *(const short8v*)&Al[wave * 16 + fr][fg * 8];
#pragma unroll
        for (int c = 0; c < 8; ++c) {
            short8v bh = *(const short8v*)&Bh[c * 16 + fr][fg * 8];
            short8v bl = *(const short8v*)&Bl[c * 16 + fr][fg * 8];
            acc[c] = __builtin_amdgcn_mfma_f32_16x16x32_bf16(ah, bh, acc[c], 0, 0, 0);
            acc[c] = __builtin_amdgcn_mfma_f32_16x16x32_bf16(ah, bl, acc[c], 0, 0, 0);
            acc[c] = __builtin_amdgcn_mfma_f32_16x16x32_bf16(al, bh, acc[c], 0, 0, 0);
        }
    }

    if (qs) {       // reduce across the 8 k-chunk threads sharing a row
#pragma unroll
        for (int off = 1; off < 8; off <<= 1) {
#pragma unroll
            for (int h = 0; h < 4; ++h) {
                qp0[h] += __shfl_xor(qp0[h], off, 64);
                qp1[h] += __shfl_xor(qp1[h], off, 64);
                kp0[h] += __shfl_xor(kp0[h], off, 64);
                kp1[h] += __shfl_xor(kp1[h], off, 64);
            }
        }
        if ((tid & 7) == 0) {
            int ra = row0 + sr, rb = row0 + sr + 32;
            if (ra < M) {
                *(float4*)&qs[(size_t)ra * HD] = make_float4(qp0[0], qp0[1], qp0[2], qp0[3]);
                *(float4*)&ks[(size_t)ra * HD] = make_float4(kp0[0], kp0[1], kp0[2], kp0[3]);
            }
            if (rb < M) {
                *(float4*)&qs[(size_t)rb * HD] = make_float4(qp1[0], qp1[1], qp1[2], qp1[3]);
                *(float4*)&ks[(size_t)rb * HD] = make_float4(kp1[0], kp1[1], kp1[2], kp1[3]);
            }
        }
    }

#pragma unroll
    for (int c = 0; c < 8; ++c) {
        float bv = bias ? bias[c * 16 + fr] : 0.f;
#pragma unroll
        for (int i = 0; i < 4; ++i) {
            int row = row0 + wave * 16 + fg * 4 + i;
            if (row < M) C[(size_t)row * DD + c * 16 + fr] = acc[c][i] + bv;
        }
    }
}

// ---------------------------------------------------------------------------
// CSR build: histogram + hierarchical 3-kernel scan + packed scatter.
// ---------------------------------------------------------------------------
__global__ __launch_bounds__(256) void csr_count(
    const int* __restrict__ dstv, int* __restrict__ deg, int E)
{
    int t = blockIdx.x * 256 + threadIdx.x;
    if (t < E) atomicAdd(&deg[dstv[t]], 1);
}

__global__ __launch_bounds__(SCAN_T) void scan_partial(
    const int* __restrict__ deg, int* __restrict__ blksum, int N)
{
    __shared__ int red[SCAN_T];
    int chunk = (N + SCAN_B - 1) / SCAN_B;
    int b0 = blockIdx.x * chunk;
    int e0 = b0 + chunk; if (e0 > N) e0 = N;
    int s = 0;
    for (int i = b0 + threadIdx.x; i < e0; i += SCAN_T) s += deg[i];
    red[threadIdx.x] = s;
    __syncthreads();
    for (int off = SCAN_T / 2; off > 0; off >>= 1) {
        if (threadIdx.x < off) red[threadIdx.x] += red[threadIdx.x + off];
        __syncthreads();
    }
    if (threadIdx.x == 0) blksum[blockIdx.x] = red[0];
}

__global__ __launch_bounds__(64) void scan_blk(
    const int* __restrict__ blksum, int* __restrict__ blkoff)
{
    if (threadIdx.x == 0) {
        int acc = 0;
        for (int i = 0; i < SCAN_B; ++i) { blkoff[i] = acc; acc += blksum[i]; }
        blkoff[SCAN_B] = acc;
    }
}

__global__ __launch_bounds__(SCAN_T) void scan_final(
    const int* __restrict__ deg, const int* __restrict__ blkoff,
    int* __restrict__ row_ptr, int N)
{
    __shared__ int tsum[SCAN_T];
    int tid = threadIdx.x;
    int chunk = (N + SCAN_B - 1) / SCAN_B;
    int b0 = blockIdx.x * chunk;
    int e0 = b0 + chunk; if (e0 > N) e0 = N;
    int tchunk = (chunk + SCAN_T - 1) / SCAN_T;
    int tb = b0 + tid * tchunk;
    int te = tb + tchunk; if (te > e0) te = e0;
    int s = 0;
    for (int i = tb; i < te; ++i) s += deg[i];
    tsum[tid] = s;
    __syncthreads();
    for (int off = 1; off < SCAN_T; off <<= 1) {
        int v = (tid >= off) ? tsum[tid - off] : 0;
        __syncthreads();
        tsum[tid] += v;
        __syncthreads();
    }
    int base = blkoff[blockIdx.x] + ((tid == 0) ? 0 : tsum[tid - 1]);
    for (int i = tb; i < te; ++i) { row_ptr[i] = base; base += deg[i]; }
    if (blockIdx.x == SCAN_B - 1 && tid == SCAN_T - 1) row_ptr[N] = blkoff[SCAN_B];
}

__global__ __launch_bounds__(256) void csr_scatter(
    const int* __restrict__ srcv, const int* __restrict__ dstv,
    const int* __restrict__ etype, const float* __restrict__ ew,
    const int* __restrict__ row_ptr, int* __restrict__ cursor,
    int4* __restrict__ c_pack, int E)
{
    int e = blockIdx.x * 256 + threadIdx.x;
    if (e >= E) return;
    int d = dstv[e];
    int p = row_ptr[d] + atomicAdd(&cursor[d], 1);
    c_pack[p] = make_int4(srcv[e], etype[e], __float_as_int(ew[e]), 0);
}

// ---------------------------------------------------------------------------
// Fused per-layer edge+softmax+aggregate+epilogue. One wave per dst node.
// ---------------------------------------------------------------------------
__global__ __launch_bounds__(256) void fused_conv(
    const int* __restrict__ row_ptr, const int4* __restrict__ c_pack,
    const float* __restrict__ qs, const float* __restrict__ ks,
    const float* __restrict__ esum, const float* __restrict__ gate,
    const float* __restrict__ v, const float* __restrict__ bias,
    float* __restrict__ out, int N, int do_elu)
{
    int gw = (blockIdx.x * 256 + threadIdx.x) >> 6;   // global wave id = node
    int lane = threadIdx.x & 63;
    if (gw >= N) return;
    const int n = gw;
    const int beg = row_ptr[n], end = row_ptr[n + 1];
    const int c0 = lane * 2;
    const int h = lane >> 4;
    const float qh = qs[(size_t)n * HD + h];
    const float gh = gate[h];
    const float sc = 0.17677669529663687f;   // 1/sqrt(32)

    float num0 = 0.f, num1 = 0.f, den = 0.f;

    int j = beg;
    int4 p;
    if (j < end) p = c_pack[j];
    while (j < end) {
        int4 cur = p;
        ++j;
        if (j < end) p = c_pack[j];
        int s = cur.x, r = cur.y;
        float w = __int_as_float(cur.z);
        float kh = ks[(size_t)s * HD + h];
        float eh = esum[(size_t)r * HD + h];
        float2 vv = *(const float2*)&v[(size_t)s * DD + c0];
        float a = (qh + kh + eh) * sc + gh * w;
        a = a > 0.f ? a : 0.2f * a;
        float e = __expf(a);
        den += e;
        num0 = fmaf(e, vv.x, num0);
        num1 = fmaf(e, vv.y, num1);
    }

    float inv = 1.f / (den + 1e-16f);
    float r0 = num0 * inv + bias[c0];
    float r1 = num1 * inv + bias[c0 + 1];
    if (do_elu) {
        r0 = r0 > 0.f ? r0 : expm1f(r0);
        r1 = r1 > 0.f ? r1 : expm1f(r1);
    }
    *(float2*)&out[(size_t)n * DD + c0] = make_float2(r0, r1);
}

// ---------------------------------------------------------------------------
extern "C" void kernel_launch(void* const* d_in, const int* in_sizes, int n_in,
                              void* d_out, int out_size, void* d_ws, size_t ws_size,
                              hipStream_t stream)
{
    const int*   entity = (const int*)d_in[0];
    const int*   eidx   = (const int*)d_in[1];
    const int*   etype  = (const int*)d_in[2];
    const float* ew     = (const float*)d_in[3];
    const float* ent    = (const float*)d_in[4];
    const float* pw     = (const float*)d_in[5];
    const float* pb     = (const float*)d_in[6];
    const float* rel    = (const float*)d_in[7];
    const float* Wq     = (const float*)d_in[8];
    const float* Wk     = (const float*)d_in[9];
    const float* Wv     = (const float*)d_in[10];
    const float* We     = (const float*)d_in[11];
    const float* gate   = (const float*)d_in[12];
    const float* cb     = (const float*)d_in[13];

    const int N = in_sizes[0];
    const int E = in_sizes[2];
    const int F = in_sizes[4] / N;     // 256
    const int R = in_sizes[7] / DD;    // 200

    const int* srcv = eidx;
    const int* dstv = eidx + E;

    float* ws = (float*)d_ws;
    size_t o = 0;
    float* xbuf    = ws + o; o += (size_t)N * DD;
    float* vbuf    = ws + o; o += (size_t)N * DD;
    float* qs      = ws + o; o += (size_t)N * HD;
    float* ks      = ws + o; o += (size_t)N * HD;
    float* Wqh     = ws + o; o += 2 * DD * HD;
    float* Wkh     = ws + o; o += 2 * DD * HD;
    float* esum    = ws + o; o += (size_t)2 * R * HD;
    int*   deg     = (int*)(ws + o); o += N;
    int*   cursor  = (int*)(ws + o); o += N;
    int*   row_ptr = (int*)(ws + o); o += (size_t)N + 1;
    int*   blksum  = (int*)(ws + o); o += SCAN_B;
    int*   blkoff  = (int*)(ws + o); o += SCAN_B + 1;
    o = (o + 3) & ~(size_t)3;                       // 16B-align
    int4*  c_pack  = (int4*)(ws + o); o += (size_t)E * 4;
    unsigned short* btp_h = (unsigned short*)(ws + o); o += 128 * 256 / 2;
    unsigned short* btp_l = (unsigned short*)(ws + o); o += 128 * 256 / 2;
    unsigned short* btv_h = (unsigned short*)(ws + o); o += 2 * DD * DD / 2;
    unsigned short* btv_l = (unsigned short*)(ws + o); o += 2 * DD * DD / 2;

    prep_kernel<<<1, 256, 0, stream>>>(Wq, Wk, We, rel, Wqh, Wkh, esum, R);
    prep_bt<<<(128 * 256 + 2 * DD * DD + 255) / 256, 256, 0, stream>>>(
        pw, Wv, btp_h, btp_l, btv_h, btv_l);

    // CSR build (layer-independent, built once)
    hipMemsetAsync(deg, 0, (size_t)2 * N * sizeof(int), stream);  // deg + cursor
    csr_count<<<(E + 255) / 256, 256, 0, stream>>>(dstv, deg, E);
    scan_partial<<<SCAN_B, SCAN_T, 0, stream>>>(deg, blksum, N);
    scan_blk<<<1, 64, 0, stream>>>(blksum, blkoff);
    scan_final<<<SCAN_B, SCAN_T, 0, stream>>>(deg, blkoff, row_ptr, N);
    csr_scatter<<<(E + 255) / 256, 256, 0, stream>>>(
        srcv, dstv, etype, ew, row_ptr, cursor, c_pack, E);

    const int gblk = (N + 63) / 64;
    // x0 = ent_table[entity] @ proj_w + proj_b   (MFMA, K=256)
    gemm_mfma<<<gblk, 256, 0, stream>>>(
        ent, entity, btp_h, btp_l, pb, nullptr, nullptr,
        xbuf, nullptr, nullptr, N, F);

    const int fblk = (N + 3) / 4;     // one 64-lane wave per node
    for (int l = 0; l < 2; ++l) {
        gemm_mfma<<<gblk, 256, 0, stream>>>(
            xbuf, nullptr, btv_h + (size_t)l * DD * DD, btv_l + (size_t)l * DD * DD,
            nullptr, Wqh + l * DD * HD, Wkh + l * DD * HD,
            vbuf, qs, ks, N, DD);
        fused_conv<<<fblk, 256, 0, stream>>>(
            row_ptr, c_pack, qs, ks, esum + (size_t)l * R * HD,
            gate + l * HD, vbuf, cb + l * DD,
            (l == 0) ? xbuf : (float*)d_out, N, (l == 0) ? 1 : 0);
    }
}

// Round 16
// 256.564 us; speedup vs baseline: 1.1175x; 1.0354x over previous
//
#include <hip/hip_runtime.h>

#define HD 4      // heads
#define DD 128    // model dim
#define CC 32     // channels per head
#define SCAN_B 64
#define SCAN_T 256

typedef float  f32x4   __attribute__((ext_vector_type(4)));
typedef short  short8v __attribute__((ext_vector_type(8)));

__device__ __forceinline__ unsigned short f2bf(float x) {
    unsigned u = __float_as_uint(x);
    return (unsigned short)((u + 0x7FFFu + ((u >> 16) & 1u)) >> 16);
}
__device__ __forceinline__ float bf2f(unsigned short h) {
    return __uint_as_float((unsigned)h << 16);
}

// ---------------------------------------------------------------------------
// Precompute per-head weight column-sums and per-relation esum table.
// ---------------------------------------------------------------------------
__global__ __launch_bounds__(256) void prep_kernel(
    const float* __restrict__ Wq, const float* __restrict__ Wk,
    const float* __restrict__ We, const float* __restrict__ rel,
    float* __restrict__ Wqh, float* __restrict__ Wkh,
    float* __restrict__ esum, int R)
{
    __shared__ float WehS[2][DD][HD];   // 4 KB
    int tid = threadIdx.x;
    for (int i = tid; i < 2 * DD * HD; i += 256) {
        int l = i / (DD * HD);
        int d = (i / HD) % DD;
        int h = i % HD;
        const float* bq = Wq + ((size_t)l * DD + d) * DD + h * CC;
        const float* bk = Wk + ((size_t)l * DD + d) * DD + h * CC;
        const float* be = We + ((size_t)l * DD + d) * DD + h * CC;
        float sq = 0.f, sk = 0.f, se = 0.f;
        for (int c = 0; c < CC; ++c) { sq += bq[c]; sk += bk[c]; se += be[c]; }
        Wqh[i] = sq; Wkh[i] = sk; WehS[l][d][h] = se;
    }
    __syncthreads();
    for (int i = tid; i < 2 * R * HD; i += 256) {
        int l = i / (R * HD);
        int r = (i / HD) % R;
        int h = i % HD;
        const float* rp = rel + (size_t)r * DD;
        float a = 0.f;
        for (int d = 0; d < DD; ++d) a += rp[d] * WehS[l][d][h];
        esum[i] = a;
    }
}

// ---------------------------------------------------------------------------
// Transposed bf16 (hi-only) weight tables:
//   btp[col][k] for proj_w[256][128]; btv[(l*128+col)][k] for Wv[l][128][128]
// ---------------------------------------------------------------------------
__global__ __launch_bounds__(256) void prep_bt(
    const float* __restrict__ pw, const float* __restrict__ Wv,
    unsigned short* __restrict__ btp, unsigned short* __restrict__ btv)
{
    int t = blockIdx.x * 256 + threadIdx.x;
    if (t < 128 * 256) {
        int col = t >> 8, k = t & 255;
        btp[(size_t)col * 256 + k] = f2bf(pw[(size_t)k * DD + col]);
    } else if (t < 128 * 256 + 2 * DD * DD) {
        int u = t - 128 * 256;
        int l = u >> 14;
        int r = u & 16383;
        int col = r >> 7, k = r & 127;
        btv[((size_t)l * DD + col) * DD + k] = f2bf(Wv[((size_t)l * DD + k) * DD + col]);
    }
}

// ---------------------------------------------------------------------------
// Split-bf16 MFMA GEMM, chunked at BK=128 with ONE staging phase per chunk.
// C[M x 128] = gather(A)[M x K] @ B (+bias); 2-pass (Ah + Al) x Bh.
// Block: 64 rows x 128 cols, 4 waves; wave w owns row-tile w (16 rows).
// LDS is fragment-contiguous: every ds_read is addr = lane*16 + const.
// Frag layouts (verified m89/m91, round-15 PASS): A row=lane&15,
// k=(lane>>4)*8+j; B col=lane&15; D col=lane&15, row=(lane>>4)*4+i.
// ---------------------------------------------------------------------------
__global__ __launch_bounds__(256) void gemm_mfma(
    const float* __restrict__ A, const int* __restrict__ gather,
    const unsigned short* __restrict__ bth, const float* __restrict__ bias,
    const float* __restrict__ Wqh, const float* __restrict__ Wkh,
    float* __restrict__ C, float* __restrict__ qs, float* __restrict__ ks,
    int M, int K)
{
    __shared__ unsigned short AhL[4][4][64][8];   // 16 KB [rowtile][kstep][lane][8]
    __shared__ unsigned short AlL[4][4][64][8];   // 16 KB
    __shared__ unsigned short BhL[4][8][64][8];   // 32 KB [kstep][coltile][lane][8]
    __shared__ float wq[DD * HD], wk[DD * HD];    // 4 KB

    const int tid = threadIdx.x;
    const int wave = tid >> 6, lane = tid & 63;
    const int row0 = blockIdx.x * 64;

    if (qs) {
        for (int i = tid; i < DD * HD; i += 256) { wq[i] = Wqh[i]; wk[i] = Wkh[i]; }
    }

    // A staging: thread -> (row sr, 32-k chunk sks)
    const int sr = tid >> 2;       // 0..63
    const int sks = tid & 3;       // 0..3
    int arow = row0 + sr; if (arow >= M) arow = M - 1;
    const int ga = gather ? gather[arow] : arow;
    const float* Ap = A + (size_t)ga * K + sks * 32;

    // B staging: thread -> (col bc, 64-k half bh2)
    const int bc = tid >> 1;       // 0..127
    const int bh2 = (tid & 1) * 64;
    const unsigned short* Bp = bth + (size_t)bc * K + bh2;
    const int bct = bc >> 4, bfr = bc & 15;

    const int fr = lane & 15, fg = lane >> 4;

    f32x4 acc[8] = {};
    float qp[4] = {}, kp[4] = {};

    const int nch = K >> 7;        // 128-wide chunks
    for (int ch = 0; ch < nch; ++ch) {
        float4 a[8];
#pragma unroll
        for (int i = 0; i < 8; ++i) a[i] = *(const float4*)(Ap + ch * 128 + i * 4);
        short8v b[8];
#pragma unroll
        for (int i = 0; i < 8; ++i) b[i] = *(const short8v*)(Bp + ch * 128 + i * 8);

        if (ch) __syncthreads();   // prior chunk's compute done before overwrite

        // ---- write A fragments (hi/lo) ----
        {
            const int rt = sr >> 4, frr = sr & 15;
#pragma unroll
            for (int g = 0; g < 4; ++g) {
                float vv[8] = {a[g*2].x, a[g*2].y, a[g*2].z, a[g*2].w,
                               a[g*2+1].x, a[g*2+1].y, a[g*2+1].z, a[g*2+1].w};
                short8v hv, lv;
#pragma unroll
                for (int j = 0; j < 8; ++j) {
                    unsigned short h = f2bf(vv[j]);
                    hv[j] = (short)h;
                    lv[j] = (short)f2bf(vv[j] - bf2f(h));
                }
                *(short8v*)&AhL[rt][sks][g * 16 + frr][0] = hv;
                *(short8v*)&AlL[rt][sks][g * 16 + frr][0] = lv;
            }
        }
        // ---- fused qk partials from exact fp32 A ----
        if (qs) {
#pragma unroll
            for (int i = 0; i < 8; ++i) {
                const float arr[4] = {a[i].x, a[i].y, a[i].z, a[i].w};
#pragma unroll
                for (int j = 0; j < 4; ++j) {
                    int d = ch * 128 + sks * 32 + i * 4 + j;
                    float4 qw = *(const float4*)&wq[d * HD];
                    float4 kw = *(const float4*)&wk[d * HD];
                    qp[0] += arr[j] * qw.x; qp[1] += arr[j] * qw.y;
                    qp[2] += arr[j] * qw.z; qp[3] += arr[j] * qw.w;
                    kp[0] += arr[j] * kw.x; kp[1] += arr[j] * kw.y;
                    kp[2] += arr[j] * kw.z; kp[3] += arr[j] * kw.w;
                }
            }
        }
        // ---- write B fragments ----
#pragma unroll
        for (int g = 0; g < 8; ++g) {
            int kk = bh2 + g * 8;
            int ksb = kk >> 5, fgb = (kk & 31) >> 3;
            *(short8v*)&BhL[ksb][bct][fgb * 16 + bfr][0] = b[g];
        }
        __syncthreads();

        // ---- MFMA: 4 ksteps x 8 col-tiles x 2 passes ----
#pragma unroll
        for (int ksc = 0; ksc < 4; ++ksc) {
            short8v ah = *(const short8v*)&AhL[wave][ksc][lane][0];
            short8v al = *(const short8v*)&AlL[wave][ksc][lane][0];
#pragma unroll
            for (int c = 0; c < 8; ++c) {
                short8v bh = *(const short8v*)&BhL[ksc][c][lane][0];
                acc[c] = __builtin_amdgcn_mfma_f32_16x16x32_bf16(ah, bh, acc[c], 0, 0, 0);
                acc[c] = __builtin_amdgcn_mfma_f32_16x16x32_bf16(al, bh, acc[c], 0, 0, 0);
            }
        }
    }

    if (qs) {      // reduce across the 4 adjacent lanes sharing a row
#pragma unroll
        for (int off = 1; off < 4; off <<= 1) {
#pragma unroll
            for (int h = 0; h < 4; ++h) {
                qp[h] += __shfl_xor(qp[h], off, 64);
                kp[h] += __shfl_xor(kp[h], off, 64);
            }
        }
        if ((tid & 3) == 0) {
            int row = row0 + sr;
            if (row < M) {
                *(float4*)&qs[(size_t)row * HD] = make_float4(qp[0], qp[1], qp[2], qp[3]);
                *(float4*)&ks[(size_t)row * HD] = make_float4(kp[0], kp[1], kp[2], kp[3]);
            }
        }
    }

#pragma unroll
    for (int c = 0; c < 8; ++c) {
        float bv = bias ? bias[c * 16 + fr] : 0.f;
#pragma unroll
        for (int i = 0; i < 4; ++i) {
            int row = row0 + wave * 16 + fg * 4 + i;
            if (row < M) C[(size_t)row * DD + c * 16 + fr] = acc[c][i] + bv;
        }
    }
}

// ---------------------------------------------------------------------------
// CSR build: histogram + hierarchical 3-kernel scan + packed scatter.
// ---------------------------------------------------------------------------
__global__ __launch_bounds__(256) void csr_count(
    const int* __restrict__ dstv, int* __restrict__ deg, int E)
{
    int t = blockIdx.x * 256 + threadIdx.x;
    if (t < E) atomicAdd(&deg[dstv[t]], 1);
}

__global__ __launch_bounds__(SCAN_T) void scan_partial(
    const int* __restrict__ deg, int* __restrict__ blksum, int N)
{
    __shared__ int red[SCAN_T];
    int chunk = (N + SCAN_B - 1) / SCAN_B;
    int b0 = blockIdx.x * chunk;
    int e0 = b0 + chunk; if (e0 > N) e0 = N;
    int s = 0;
    for (int i = b0 + threadIdx.x; i < e0; i += SCAN_T) s += deg[i];
    red[threadIdx.x] = s;
    __syncthreads();
    for (int off = SCAN_T / 2; off > 0; off >>= 1) {
        if (threadIdx.x < off) red[threadIdx.x] += red[threadIdx.x + off];
        __syncthreads();
    }
    if (threadIdx.x == 0) blksum[blockIdx.x] = red[0];
}

__global__ __launch_bounds__(64) void scan_blk(
    const int* __restrict__ blksum, int* __restrict__ blkoff)
{
    if (threadIdx.x == 0) {
        int acc = 0;
        for (int i = 0; i < SCAN_B; ++i) { blkoff[i] = acc; acc += blksum[i]; }
        blkoff[SCAN_B] = acc;
    }
}

__global__ __launch_bounds__(SCAN_T) void scan_final(
    const int* __restrict__ deg, const int* __restrict__ blkoff,
    int* __restrict__ row_ptr, int N)
{
    __shared__ int tsum[SCAN_T];
    int tid = threadIdx.x;
    int chunk = (N + SCAN_B - 1) / SCAN_B;
    int b0 = blockIdx.x * chunk;
    int e0 = b0 + chunk; if (e0 > N) e0 = N;
    int tchunk = (chunk + SCAN_T - 1) / SCAN_T;
    int tb = b0 + tid * tchunk;
    int te = tb + tchunk; if (te > e0) te = e0;
    int s = 0;
    for (int i = tb; i < te; ++i) s += deg[i];
    tsum[tid] = s;
    __syncthreads();
    for (int off = 1; off < SCAN_T; off <<= 1) {
        int v = (tid >= off) ? tsum[tid - off] : 0;
        __syncthreads();
        tsum[tid] += v;
        __syncthreads();
    }
    int base = blkoff[blockIdx.x] + ((tid == 0) ? 0 : tsum[tid - 1]);
    for (int i = tb; i < te; ++i) { row_ptr[i] = base; base += deg[i]; }
    if (blockIdx.x == SCAN_B - 1 && tid == SCAN_T - 1) row_ptr[N] = blkoff[SCAN_B];
}

__global__ __launch_bounds__(256) void csr_scatter(
    const int* __restrict__ srcv, const int* __restrict__ dstv,
    const int* __restrict__ etype, const float* __restrict__ ew,
    const int* __restrict__ row_ptr, int* __restrict__ cursor,
    int4* __restrict__ c_pack, int E)
{
    int e = blockIdx.x * 256 + threadIdx.x;
    if (e >= E) return;
    int d = dstv[e];
    int p = row_ptr[d] + atomicAdd(&cursor[d], 1);
    c_pack[p] = make_int4(srcv[e], etype[e], __float_as_int(ew[e]), 0);
}

// ---------------------------------------------------------------------------
// Fused per-layer edge+softmax+aggregate+epilogue. One wave per dst node.
// ---------------------------------------------------------------------------
__global__ __launch_bounds__(256) void fused_conv(
    const int* __restrict__ row_ptr, const int4* __restrict__ c_pack,
    const float* __restrict__ qs, const float* __restrict__ ks,
    const float* __restrict__ esum, const float* __restrict__ gate,
    const float* __restrict__ v, const float* __restrict__ bias,
    float* __restrict__ out, int N, int do_elu)
{
    int gw = (blockIdx.x * 256 + threadIdx.x) >> 6;   // global wave id = node
    int lane = threadIdx.x & 63;
    if (gw >= N) return;
    const int n = gw;
    const int beg = row_ptr[n], end = row_ptr[n + 1];
    const int c0 = lane * 2;
    const int h = lane >> 4;
    const float qh = qs[(size_t)n * HD + h];
    const float gh = gate[h];
    const float sc = 0.17677669529663687f;   // 1/sqrt(32)

    float num0 = 0.f, num1 = 0.f, den = 0.f;

    int j = beg;
    int4 p;
    if (j < end) p = c_pack[j];
    while (j < end) {
        int4 cur = p;
        ++j;
        if (j < end) p = c_pack[j];
        int s = cur.x, r = cur.y;
        float w = __int_as_float(cur.z);
        float kh = ks[(size_t)s * HD + h];
        float eh = esum[(size_t)r * HD + h];
        float2 vv = *(const float2*)&v[(size_t)s * DD + c0];
        float a = (qh + kh + eh) * sc + gh * w;
        a = a > 0.f ? a : 0.2f * a;
        float e = __expf(a);
        den += e;
        num0 = fmaf(e, vv.x, num0);
        num1 = fmaf(e, vv.y, num1);
    }

    float inv = 1.f / (den + 1e-16f);
    float r0 = num0 * inv + bias[c0];
    float r1 = num1 * inv + bias[c0 + 1];
    if (do_elu) {
        r0 = r0 > 0.f ? r0 : expm1f(r0);
        r1 = r1 > 0.f ? r1 : expm1f(r1);
    }
    *(float2*)&out[(size_t)n * DD + c0] = make_float2(r0, r1);
}

// ---------------------------------------------------------------------------
extern "C" void kernel_launch(void* const* d_in, const int* in_sizes, int n_in,
                              void* d_out, int out_size, void* d_ws, size_t ws_size,
                              hipStream_t stream)
{
    const int*   entity = (const int*)d_in[0];
    const int*   eidx   = (const int*)d_in[1];
    const int*   etype  = (const int*)d_in[2];
    const float* ew     = (const float*)d_in[3];
    const float* ent    = (const float*)d_in[4];
    const float* pw     = (const float*)d_in[5];
    const float* pb     = (const float*)d_in[6];
    const float* rel    = (const float*)d_in[7];
    const float* Wq     = (const float*)d_in[8];
    const float* Wk     = (const float*)d_in[9];
    const float* Wv     = (const float*)d_in[10];
    const float* We     = (const float*)d_in[11];
    const float* gate   = (const float*)d_in[12];
    const float* cb     = (const float*)d_in[13];

    const int N = in_sizes[0];
    const int E = in_sizes[2];
    const int F = in_sizes[4] / N;     // 256
    const int R = in_sizes[7] / DD;    // 200

    const int* srcv = eidx;
    const int* dstv = eidx + E;

    float* ws = (float*)d_ws;
    size_t o = 0;
    float* xbuf    = ws + o; o += (size_t)N * DD;
    float* vbuf    = ws + o; o += (size_t)N * DD;
    float* qs      = ws + o; o += (size_t)N * HD;
    float* ks      = ws + o; o += (size_t)N * HD;
    float* Wqh     = ws + o; o += 2 * DD * HD;
    float* Wkh     = ws + o; o += 2 * DD * HD;
    float* esum    = ws + o; o += (size_t)2 * R * HD;
    int*   deg     = (int*)(ws + o); o += N;
    int*   cursor  = (int*)(ws + o); o += N;
    int*   row_ptr = (int*)(ws + o); o += (size_t)N + 1;
    int*   blksum  = (int*)(ws + o); o += SCAN_B;
    int*   blkoff  = (int*)(ws + o); o += SCAN_B + 1;
    o = (o + 3) & ~(size_t)3;                       // 16B-align
    int4*  c_pack  = (int4*)(ws + o); o += (size_t)E * 4;
    unsigned short* btp = (unsigned short*)(ws + o); o += 128 * 256 / 2;
    unsigned short* btv = (unsigned short*)(ws + o); o += 2 * DD * DD / 2;

    prep_kernel<<<1, 256, 0, stream>>>(Wq, Wk, We, rel, Wqh, Wkh, esum, R);
    prep_bt<<<(128 * 256 + 2 * DD * DD + 255) / 256, 256, 0, stream>>>(
        pw, Wv, btp, btv);

    // CSR build (layer-independent, built once)
    hipMemsetAsync(deg, 0, (size_t)2 * N * sizeof(int), stream);  // deg + cursor
    csr_count<<<(E + 255) / 256, 256, 0, stream>>>(dstv, deg, E);
    scan_partial<<<SCAN_B, SCAN_T, 0, stream>>>(deg, blksum, N);
    scan_blk<<<1, 64, 0, stream>>>(blksum, blkoff);
    scan_final<<<SCAN_B, SCAN_T, 0, stream>>>(deg, blkoff, row_ptr, N);
    csr_scatter<<<(E + 255) / 256, 256, 0, stream>>>(
        srcv, dstv, etype, ew, row_ptr, cursor, c_pack, E);

    const int gblk = (N + 63) / 64;
    // x0 = ent_table[entity] @ proj_w + proj_b   (MFMA, K=256)
    gemm_mfma<<<gblk, 256, 0, stream>>>(
        ent, entity, btp, pb, nullptr, nullptr,
        xbuf, nullptr, nullptr, N, F);

    const int fblk = (N + 3) / 4;     // one 64-lane wave per node
    for (int l = 0; l < 2; ++l) {
        gemm_mfma<<<gblk, 256, 0, stream>>>(
            xbuf, nullptr, btv + (size_t)l * DD * DD, nullptr,
            Wqh + l * DD * HD, Wkh + l * DD * HD,
            vbuf, qs, ks, N, DD);
        fused_conv<<<fblk, 256, 0, stream>>>(
            row_ptr, c_pack, qs, ks, esum + (size_t)l * R * HD,
            gate + l * HD, vbuf, cb + l * DD,
            (l == 0) ? xbuf : (float*)d_out, N, (l == 0) ? 1 : 0);
    }
}

// Round 17
// 248.430 us; speedup vs baseline: 1.1541x; 1.0327x over previous
//
#include <hip/hip_runtime.h>

#define HD 4      // heads
#define DD 128    // model dim
#define CC 32     // channels per head
#define SCAN_B 64
#define SCAN_T 256

typedef float  f32x4   __attribute__((ext_vector_type(4)));
typedef short  short8v __attribute__((ext_vector_type(8)));

__device__ __forceinline__ unsigned short f2bf(float x) {
    unsigned u = __float_as_uint(x);
    return (unsigned short)((u + 0x7FFFu + ((u >> 16) & 1u)) >> 16);
}
__device__ __forceinline__ float bf2f(unsigned short h) {
    return __uint_as_float((unsigned)h << 16);
}

// ---------------------------------------------------------------------------
// Precompute per-head weight column-sums and per-relation esum table.
// ---------------------------------------------------------------------------
__global__ __launch_bounds__(256) void prep_kernel(
    const float* __restrict__ Wq, const float* __restrict__ Wk,
    const float* __restrict__ We, const float* __restrict__ rel,
    float* __restrict__ Wqh, float* __restrict__ Wkh,
    float* __restrict__ esum, int R)
{
    __shared__ float WehS[2][DD][HD];   // 4 KB
    int tid = threadIdx.x;
    for (int i = tid; i < 2 * DD * HD; i += 256) {
        int l = i / (DD * HD);
        int d = (i / HD) % DD;
        int h = i % HD;
        const float* bq = Wq + ((size_t)l * DD + d) * DD + h * CC;
        const float* bk = Wk + ((size_t)l * DD + d) * DD + h * CC;
        const float* be = We + ((size_t)l * DD + d) * DD + h * CC;
        float sq = 0.f, sk = 0.f, se = 0.f;
        for (int c = 0; c < CC; ++c) { sq += bq[c]; sk += bk[c]; se += be[c]; }
        Wqh[i] = sq; Wkh[i] = sk; WehS[l][d][h] = se;
    }
    __syncthreads();
    for (int i = tid; i < 2 * R * HD; i += 256) {
        int l = i / (R * HD);
        int r = (i / HD) % R;
        int h = i % HD;
        const float* rp = rel + (size_t)r * DD;
        float a = 0.f;
        for (int d = 0; d < DD; ++d) a += rp[d] * WehS[l][d][h];
        esum[i] = a;
    }
}

// ---------------------------------------------------------------------------
// Transposed bf16 (hi-only) weight tables:
//   btp[col][k] for proj_w[256][128]; btv[(l*128+col)][k] for Wv[l][128][128]
// ---------------------------------------------------------------------------
__global__ __launch_bounds__(256) void prep_bt(
    const float* __restrict__ pw, const float* __restrict__ Wv,
    unsigned short* __restrict__ btp, unsigned short* __restrict__ btv)
{
    int t = blockIdx.x * 256 + threadIdx.x;
    if (t < 128 * 256) {
        int col = t >> 8, k = t & 255;
        btp[(size_t)col * 256 + k] = f2bf(pw[(size_t)k * DD + col]);
    } else if (t < 128 * 256 + 2 * DD * DD) {
        int u = t - 128 * 256;
        int l = u >> 14;
        int r = u & 16383;
        int col = r >> 7, k = r & 127;
        btv[((size_t)l * DD + col) * DD + k] = f2bf(Wv[((size_t)l * DD + k) * DD + col]);
    }
}

// ---------------------------------------------------------------------------
// Split-bf16 MFMA GEMM, chunked at BK=128 with ONE staging phase per chunk.
// (unchanged from round 16 — dropped out of top-5)
// ---------------------------------------------------------------------------
__global__ __launch_bounds__(256) void gemm_mfma(
    const float* __restrict__ A, const int* __restrict__ gather,
    const unsigned short* __restrict__ bth, const float* __restrict__ bias,
    const float* __restrict__ Wqh, const float* __restrict__ Wkh,
    float* __restrict__ C, float* __restrict__ qs, float* __restrict__ ks,
    int M, int K)
{
    __shared__ unsigned short AhL[4][4][64][8];   // 16 KB [rowtile][kstep][lane][8]
    __shared__ unsigned short AlL[4][4][64][8];   // 16 KB
    __shared__ unsigned short BhL[4][8][64][8];   // 32 KB [kstep][coltile][lane][8]
    __shared__ float wq[DD * HD], wk[DD * HD];    // 4 KB

    const int tid = threadIdx.x;
    const int wave = tid >> 6, lane = tid & 63;
    const int row0 = blockIdx.x * 64;

    if (qs) {
        for (int i = tid; i < DD * HD; i += 256) { wq[i] = Wqh[i]; wk[i] = Wkh[i]; }
    }

    const int sr = tid >> 2;       // 0..63
    const int sks = tid & 3;       // 0..3
    int arow = row0 + sr; if (arow >= M) arow = M - 1;
    const int ga = gather ? gather[arow] : arow;
    const float* Ap = A + (size_t)ga * K + sks * 32;

    const int bc = tid >> 1;       // 0..127
    const int bh2 = (tid & 1) * 64;
    const unsigned short* Bp = bth + (size_t)bc * K + bh2;
    const int bct = bc >> 4, bfr = bc & 15;

    const int fr = lane & 15, fg = lane >> 4;

    f32x4 acc[8] = {};
    float qp[4] = {}, kp[4] = {};

    const int nch = K >> 7;        // 128-wide chunks
    for (int ch = 0; ch < nch; ++ch) {
        float4 a[8];
#pragma unroll
        for (int i = 0; i < 8; ++i) a[i] = *(const float4*)(Ap + ch * 128 + i * 4);
        short8v b[8];
#pragma unroll
        for (int i = 0; i < 8; ++i) b[i] = *(const short8v*)(Bp + ch * 128 + i * 8);

        if (ch) __syncthreads();

        {
            const int rt = sr >> 4, frr = sr & 15;
#pragma unroll
            for (int g = 0; g < 4; ++g) {
                float vv[8] = {a[g*2].x, a[g*2].y, a[g*2].z, a[g*2].w,
                               a[g*2+1].x, a[g*2+1].y, a[g*2+1].z, a[g*2+1].w};
                short8v hv, lv;
#pragma unroll
                for (int j = 0; j < 8; ++j) {
                    unsigned short h = f2bf(vv[j]);
                    hv[j] = (short)h;
                    lv[j] = (short)f2bf(vv[j] - bf2f(h));
                }
                *(short8v*)&AhL[rt][sks][g * 16 + frr][0] = hv;
                *(short8v*)&AlL[rt][sks][g * 16 + frr][0] = lv;
            }
        }
        if (qs) {
#pragma unroll
            for (int i = 0; i < 8; ++i) {
                const float arr[4] = {a[i].x, a[i].y, a[i].z, a[i].w};
#pragma unroll
                for (int j = 0; j < 4; ++j) {
                    int d = ch * 128 + sks * 32 + i * 4 + j;
                    float4 qw = *(const float4*)&wq[d * HD];
                    float4 kw = *(const float4*)&wk[d * HD];
                    qp[0] += arr[j] * qw.x; qp[1] += arr[j] * qw.y;
                    qp[2] += arr[j] * qw.z; qp[3] += arr[j] * qw.w;
                    kp[0] += arr[j] * kw.x; kp[1] += arr[j] * kw.y;
                    kp[2] += arr[j] * kw.z; kp[3] += arr[j] * kw.w;
                }
            }
        }
#pragma unroll
        for (int g = 0; g < 8; ++g) {
            int kk = bh2 + g * 8;
            int ksb = kk >> 5, fgb = (kk & 31) >> 3;
            *(short8v*)&BhL[ksb][bct][fgb * 16 + bfr][0] = b[g];
        }
        __syncthreads();

#pragma unroll
        for (int ksc = 0; ksc < 4; ++ksc) {
            short8v ah = *(const short8v*)&AhL[wave][ksc][lane][0];
            short8v al = *(const short8v*)&AlL[wave][ksc][lane][0];
#pragma unroll
            for (int c = 0; c < 8; ++c) {
                short8v bh = *(const short8v*)&BhL[ksc][c][lane][0];
                acc[c] = __builtin_amdgcn_mfma_f32_16x16x32_bf16(ah, bh, acc[c], 0, 0, 0);
                acc[c] = __builtin_amdgcn_mfma_f32_16x16x32_bf16(al, bh, acc[c], 0, 0, 0);
            }
        }
    }

    if (qs) {
#pragma unroll
        for (int off = 1; off < 4; off <<= 1) {
#pragma unroll
            for (int h = 0; h < 4; ++h) {
                qp[h] += __shfl_xor(qp[h], off, 64);
                kp[h] += __shfl_xor(kp[h], off, 64);
            }
        }
        if ((tid & 3) == 0) {
            int row = row0 + sr;
            if (row < M) {
                *(float4*)&qs[(size_t)row * HD] = make_float4(qp[0], qp[1], qp[2], qp[3]);
                *(float4*)&ks[(size_t)row * HD] = make_float4(kp[0], kp[1], kp[2], kp[3]);
            }
        }
    }

#pragma unroll
    for (int c = 0; c < 8; ++c) {
        float bv = bias ? bias[c * 16 + fr] : 0.f;
#pragma unroll
        for (int i = 0; i < 4; ++i) {
            int row = row0 + wave * 16 + fg * 4 + i;
            if (row < M) C[(size_t)row * DD + c * 16 + fr] = acc[c][i] + bv;
        }
    }
}

// ---------------------------------------------------------------------------
// CSR build: histogram + hierarchical 3-kernel scan + packed scatter.
// ---------------------------------------------------------------------------
__global__ __launch_bounds__(256) void csr_count(
    const int* __restrict__ dstv, int* __restrict__ deg, int E)
{
    int t = blockIdx.x * 256 + threadIdx.x;
    if (t < E) atomicAdd(&deg[dstv[t]], 1);
}

__global__ __launch_bounds__(SCAN_T) void scan_partial(
    const int* __restrict__ deg, int* __restrict__ blksum, int N)
{
    __shared__ int red[SCAN_T];
    int chunk = (N + SCAN_B - 1) / SCAN_B;
    int b0 = blockIdx.x * chunk;
    int e0 = b0 + chunk; if (e0 > N) e0 = N;
    int s = 0;
    for (int i = b0 + threadIdx.x; i < e0; i += SCAN_T) s += deg[i];
    red[threadIdx.x] = s;
    __syncthreads();
    for (int off = SCAN_T / 2; off > 0; off >>= 1) {
        if (threadIdx.x < off) red[threadIdx.x] += red[threadIdx.x + off];
        __syncthreads();
    }
    if (threadIdx.x == 0) blksum[blockIdx.x] = red[0];
}

__global__ __launch_bounds__(64) void scan_blk(
    const int* __restrict__ blksum, int* __restrict__ blkoff)
{
    if (threadIdx.x == 0) {
        int acc = 0;
        for (int i = 0; i < SCAN_B; ++i) { blkoff[i] = acc; acc += blksum[i]; }
        blkoff[SCAN_B] = acc;
    }
}

__global__ __launch_bounds__(SCAN_T) void scan_final(
    const int* __restrict__ deg, const int* __restrict__ blkoff,
    int* __restrict__ row_ptr, int N)
{
    __shared__ int tsum[SCAN_T];
    int tid = threadIdx.x;
    int chunk = (N + SCAN_B - 1) / SCAN_B;
    int b0 = blockIdx.x * chunk;
    int e0 = b0 + chunk; if (e0 > N) e0 = N;
    int tchunk = (chunk + SCAN_T - 1) / SCAN_T;
    int tb = b0 + tid * tchunk;
    int te = tb + tchunk; if (te > e0) te = e0;
    int s = 0;
    for (int i = tb; i < te; ++i) s += deg[i];
    tsum[tid] = s;
    __syncthreads();
    for (int off = 1; off < SCAN_T; off <<= 1) {
        int v = (tid >= off) ? tsum[tid - off] : 0;
        __syncthreads();
        tsum[tid] += v;
        __syncthreads();
    }
    int base = blkoff[blockIdx.x] + ((tid == 0) ? 0 : tsum[tid - 1]);
    for (int i = tb; i < te; ++i) { row_ptr[i] = base; base += deg[i]; }
    if (blockIdx.x == SCAN_B - 1 && tid == SCAN_T - 1) row_ptr[N] = blkoff[SCAN_B];
}

__global__ __launch_bounds__(256) void csr_scatter(
    const int* __restrict__ srcv, const int* __restrict__ dstv,
    const int* __restrict__ etype, const float* __restrict__ ew,
    const int* __restrict__ row_ptr, int* __restrict__ cursor,
    int4* __restrict__ c_pack, int E)
{
    int e = blockIdx.x * 256 + threadIdx.x;
    if (e >= E) return;
    int d = dstv[e];
    int p = row_ptr[d] + atomicAdd(&cursor[d], 1);
    c_pack[p] = make_int4(srcv[e], etype[e], __float_as_int(ew[e]), 0);
}

// ---------------------------------------------------------------------------
// Fused per-layer edge+softmax+aggregate+epilogue. One wave per dst node.
// Batch-4 edge loop: 4 pack records loaded together, then all 12 dependent
// loads issued before any compute — latency exposed once per 4 edges.
// exp via exp2f with log2(e) prefolded (leaky_relu is positively homogeneous).
// ---------------------------------------------------------------------------
__global__ __launch_bounds__(256) void fused_conv(
    const int* __restrict__ row_ptr, const int4* __restrict__ c_pack,
    const float* __restrict__ qs, const float* __restrict__ ks,
    const float* __restrict__ esum, const float* __restrict__ gate,
    const float* __restrict__ v, const float* __restrict__ bias,
    float* __restrict__ out, int N, int do_elu)
{
    int gw = (blockIdx.x * 256 + threadIdx.x) >> 6;   // global wave id = node
    int lane = threadIdx.x & 63;
    if (gw >= N) return;
    const int n = gw;
    const int beg = row_ptr[n], end = row_ptr[n + 1];
    const int c0 = lane * 2;
    const int h = lane >> 4;
    const float L2E = 1.4426950408889634f;
    const float scL = 0.17677669529663687f * 1.4426950408889634f;  // (1/sqrt32)*log2e
    const float qh = qs[(size_t)n * HD + h];
    const float ghL = gate[h] * L2E;

    float num0 = 0.f, num1 = 0.f, den = 0.f;

    int j = beg;
    for (; j + 4 <= end; j += 4) {
        int4 p0 = c_pack[j];
        int4 p1 = c_pack[j + 1];
        int4 p2 = c_pack[j + 2];
        int4 p3 = c_pack[j + 3];
        float kh0 = ks[(size_t)p0.x * HD + h];
        float kh1 = ks[(size_t)p1.x * HD + h];
        float kh2 = ks[(size_t)p2.x * HD + h];
        float kh3 = ks[(size_t)p3.x * HD + h];
        float eh0 = esum[(size_t)p0.y * HD + h];
        float eh1 = esum[(size_t)p1.y * HD + h];
        float eh2 = esum[(size_t)p2.y * HD + h];
        float eh3 = esum[(size_t)p3.y * HD + h];
        float2 vv0 = *(const float2*)&v[(size_t)p0.x * DD + c0];
        float2 vv1 = *(const float2*)&v[(size_t)p1.x * DD + c0];
        float2 vv2 = *(const float2*)&v[(size_t)p2.x * DD + c0];
        float2 vv3 = *(const float2*)&v[(size_t)p3.x * DD + c0];
        float a0 = (qh + kh0 + eh0) * scL + ghL * __int_as_float(p0.z);
        float a1 = (qh + kh1 + eh1) * scL + ghL * __int_as_float(p1.z);
        float a2 = (qh + kh2 + eh2) * scL + ghL * __int_as_float(p2.z);
        float a3 = (qh + kh3 + eh3) * scL + ghL * __int_as_float(p3.z);
        a0 = a0 > 0.f ? a0 : 0.2f * a0;
        a1 = a1 > 0.f ? a1 : 0.2f * a1;
        a2 = a2 > 0.f ? a2 : 0.2f * a2;
        a3 = a3 > 0.f ? a3 : 0.2f * a3;
        float e0 = exp2f(a0), e1 = exp2f(a1);
        float e2 = exp2f(a2), e3 = exp2f(a3);
        den += (e0 + e1) + (e2 + e3);
        num0 = fmaf(e0, vv0.x, num0); num1 = fmaf(e0, vv0.y, num1);
        num0 = fmaf(e1, vv1.x, num0); num1 = fmaf(e1, vv1.y, num1);
        num0 = fmaf(e2, vv2.x, num0); num1 = fmaf(e2, vv2.y, num1);
        num0 = fmaf(e3, vv3.x, num0); num1 = fmaf(e3, vv3.y, num1);
    }
    for (; j < end; ++j) {
        int4 cur = c_pack[j];
        float kh = ks[(size_t)cur.x * HD + h];
        float eh = esum[(size_t)cur.y * HD + h];
        float2 vv = *(const float2*)&v[(size_t)cur.x * DD + c0];
        float a = (qh + kh + eh) * scL + ghL * __int_as_float(cur.z);
        a = a > 0.f ? a : 0.2f * a;
        float e = exp2f(a);
        den += e;
        num0 = fmaf(e, vv.x, num0);
        num1 = fmaf(e, vv.y, num1);
    }

    float inv = 1.f / (den + 1e-16f);
    float r0 = num0 * inv + bias[c0];
    float r1 = num1 * inv + bias[c0 + 1];
    if (do_elu) {
        r0 = r0 > 0.f ? r0 : expm1f(r0);
        r1 = r1 > 0.f ? r1 : expm1f(r1);
    }
    *(float2*)&out[(size_t)n * DD + c0] = make_float2(r0, r1);
}

// ---------------------------------------------------------------------------
extern "C" void kernel_launch(void* const* d_in, const int* in_sizes, int n_in,
                              void* d_out, int out_size, void* d_ws, size_t ws_size,
                              hipStream_t stream)
{
    const int*   entity = (const int*)d_in[0];
    const int*   eidx   = (const int*)d_in[1];
    const int*   etype  = (const int*)d_in[2];
    const float* ew     = (const float*)d_in[3];
    const float* ent    = (const float*)d_in[4];
    const float* pw     = (const float*)d_in[5];
    const float* pb     = (const float*)d_in[6];
    const float* rel    = (const float*)d_in[7];
    const float* Wq     = (const float*)d_in[8];
    const float* Wk     = (const float*)d_in[9];
    const float* Wv     = (const float*)d_in[10];
    const float* We     = (const float*)d_in[11];
    const float* gate   = (const float*)d_in[12];
    const float* cb     = (const float*)d_in[13];

    const int N = in_sizes[0];
    const int E = in_sizes[2];
    const int F = in_sizes[4] / N;     // 256
    const int R = in_sizes[7] / DD;    // 200

    const int* srcv = eidx;
    const int* dstv = eidx + E;

    float* ws = (float*)d_ws;
    size_t o = 0;
    float* xbuf    = ws + o; o += (size_t)N * DD;
    float* vbuf    = ws + o; o += (size_t)N * DD;
    float* qs      = ws + o; o += (size_t)N * HD;
    float* ks      = ws + o; o += (size_t)N * HD;
    float* Wqh     = ws + o; o += 2 * DD * HD;
    float* Wkh     = ws + o; o += 2 * DD * HD;
    float* esum    = ws + o; o += (size_t)2 * R * HD;
    int*   deg     = (int*)(ws + o); o += N;
    int*   cursor  = (int*)(ws + o); o += N;
    int*   row_ptr = (int*)(ws + o); o += (size_t)N + 1;
    int*   blksum  = (int*)(ws + o); o += SCAN_B;
    int*   blkoff  = (int*)(ws + o); o += SCAN_B + 1;
    o = (o + 3) & ~(size_t)3;                       // 16B-align
    int4*  c_pack  = (int4*)(ws + o); o += (size_t)E * 4;
    unsigned short* btp = (unsigned short*)(ws + o); o += 128 * 256 / 2;
    unsigned short* btv = (unsigned short*)(ws + o); o += 2 * DD * DD / 2;

    prep_kernel<<<1, 256, 0, stream>>>(Wq, Wk, We, rel, Wqh, Wkh, esum, R);
    prep_bt<<<(128 * 256 + 2 * DD * DD + 255) / 256, 256, 0, stream>>>(
        pw, Wv, btp, btv);

    // CSR build (layer-independent, built once)
    hipMemsetAsync(deg, 0, (size_t)2 * N * sizeof(int), stream);  // deg + cursor
    csr_count<<<(E + 255) / 256, 256, 0, stream>>>(dstv, deg, E);
    scan_partial<<<SCAN_B, SCAN_T, 0, stream>>>(deg, blksum, N);
    scan_blk<<<1, 64, 0, stream>>>(blksum, blkoff);
    scan_final<<<SCAN_B, SCAN_T, 0, stream>>>(deg, blkoff, row_ptr, N);
    csr_scatter<<<(E + 255) / 256, 256, 0, stream>>>(
        srcv, dstv, etype, ew, row_ptr, cursor, c_pack, E);

    const int gblk = (N + 63) / 64;
    // x0 = ent_table[entity] @ proj_w + proj_b   (MFMA, K=256)
    gemm_mfma<<<gblk, 256, 0, stream>>>(
        ent, entity, btp, pb, nullptr, nullptr,
        xbuf, nullptr, nullptr, N, F);

    const int fblk = (N + 3) / 4;     // one 64-lane wave per node
    for (int l = 0; l < 2; ++l) {
        gemm_mfma<<<gblk, 256, 0, stream>>>(
            xbuf, nullptr, btv + (size_t)l * DD * DD, nullptr,
            Wqh + l * DD * HD, Wkh + l * DD * HD,
            vbuf, qs, ks, N, DD);
        fused_conv<<<fblk, 256, 0, stream>>>(
            row_ptr, c_pack, qs, ks, esum + (size_t)l * R * HD,
            gate + l * HD, vbuf, cb + l * DD,
            (l == 0) ? xbuf : (float*)d_out, N, (l == 0) ? 1 : 0);
    }
}

// Round 19
// 234.576 us; speedup vs baseline: 1.2223x; 1.0591x over previous
//
#include <hip/hip_runtime.h>
#include <hip/hip_fp16.h>

#define HD 4      // heads
#define DD 128    // model dim
#define CC 32     // channels per head
#define SCAN_B 64
#define SCAN_T 256

typedef float  f32x4   __attribute__((ext_vector_type(4)));
typedef short  short8v __attribute__((ext_vector_type(8)));

__device__ __forceinline__ unsigned short f2bf(float x) {
    unsigned u = __float_as_uint(x);
    return (unsigned short)((u + 0x7FFFu + ((u >> 16) & 1u)) >> 16);
}
__device__ __forceinline__ float bf2f(unsigned short h) {
    return __uint_as_float((unsigned)h << 16);
}

// ---------------------------------------------------------------------------
// Precompute per-head weight column-sums and per-relation esum table.
// ---------------------------------------------------------------------------
__global__ __launch_bounds__(256) void prep_kernel(
    const float* __restrict__ Wq, const float* __restrict__ Wk,
    const float* __restrict__ We, const float* __restrict__ rel,
    float* __restrict__ Wqh, float* __restrict__ Wkh,
    float* __restrict__ esum, int R)
{
    __shared__ float WehS[2][DD][HD];   // 4 KB
    int tid = threadIdx.x;
    for (int i = tid; i < 2 * DD * HD; i += 256) {
        int l = i / (DD * HD);
        int d = (i / HD) % DD;
        int h = i % HD;
        const float* bq = Wq + ((size_t)l * DD + d) * DD + h * CC;
        const float* bk = Wk + ((size_t)l * DD + d) * DD + h * CC;
        const float* be = We + ((size_t)l * DD + d) * DD + h * CC;
        float sq = 0.f, sk = 0.f, se = 0.f;
        for (int c = 0; c < CC; ++c) { sq += bq[c]; sk += bk[c]; se += be[c]; }
        Wqh[i] = sq; Wkh[i] = sk; WehS[l][d][h] = se;
    }
    __syncthreads();
    for (int i = tid; i < 2 * R * HD; i += 256) {
        int l = i / (R * HD);
        int r = (i / HD) % R;
        int h = i % HD;
        const float* rp = rel + (size_t)r * DD;
        float a = 0.f;
        for (int d = 0; d < DD; ++d) a += rp[d] * WehS[l][d][h];
        esum[i] = a;
    }
}

// ---------------------------------------------------------------------------
// Transposed bf16 (hi-only) weight tables.
// ---------------------------------------------------------------------------
__global__ __launch_bounds__(256) void prep_bt(
    const float* __restrict__ pw, const float* __restrict__ Wv,
    unsigned short* __restrict__ btp, unsigned short* __restrict__ btv)
{
    int t = blockIdx.x * 256 + threadIdx.x;
    if (t < 128 * 256) {
        int col = t >> 8, k = t & 255;
        btp[(size_t)col * 256 + k] = f2bf(pw[(size_t)k * DD + col]);
    } else if (t < 128 * 256 + 2 * DD * DD) {
        int u = t - 128 * 256;
        int l = u >> 14;
        int r = u & 16383;
        int col = r >> 7, k = r & 127;
        btv[((size_t)l * DD + col) * DD + k] = f2bf(Wv[((size_t)l * DD + k) * DD + col]);
    }
}

// ---------------------------------------------------------------------------
// Split-bf16 MFMA GEMM, chunked at BK=128, one staging phase per chunk.
// Output: fp32 C (if Cf) or fp16 C (if Chf) — fp16 halves v-gather bytes.
// ---------------------------------------------------------------------------
__global__ __launch_bounds__(256) void gemm_mfma(
    const float* __restrict__ A, const int* __restrict__ gather,
    const unsigned short* __restrict__ bth, const float* __restrict__ bias,
    const float* __restrict__ Wqh, const float* __restrict__ Wkh,
    float* __restrict__ Cf, __half* __restrict__ Chf,
    float* __restrict__ qs, float* __restrict__ ks,
    int M, int K)
{
    __shared__ unsigned short AhL[4][4][64][8];   // 16 KB
    __shared__ unsigned short AlL[4][4][64][8];   // 16 KB
    __shared__ unsigned short BhL[4][8][64][8];   // 32 KB
    __shared__ float wq[DD * HD], wk[DD * HD];    // 4 KB

    const int tid = threadIdx.x;
    const int wave = tid >> 6, lane = tid & 63;
    const int row0 = blockIdx.x * 64;

    if (qs) {
        for (int i = tid; i < DD * HD; i += 256) { wq[i] = Wqh[i]; wk[i] = Wkh[i]; }
    }

    const int sr = tid >> 2;       // 0..63
    const int sks = tid & 3;       // 0..3
    int arow = row0 + sr; if (arow >= M) arow = M - 1;
    const int ga = gather ? gather[arow] : arow;
    const float* Ap = A + (size_t)ga * K + sks * 32;

    const int bc = tid >> 1;       // 0..127
    const int bh2 = (tid & 1) * 64;
    const unsigned short* Bp = bth + (size_t)bc * K + bh2;
    const int bct = bc >> 4, bfr = bc & 15;

    const int fr = lane & 15, fg = lane >> 4;

    f32x4 acc[8] = {};
    float qp[4] = {}, kp[4] = {};

    const int nch = K >> 7;        // 128-wide chunks
    for (int ch = 0; ch < nch; ++ch) {
        float4 a[8];
#pragma unroll
        for (int i = 0; i < 8; ++i) a[i] = *(const float4*)(Ap + ch * 128 + i * 4);
        short8v b[8];
#pragma unroll
        for (int i = 0; i < 8; ++i) b[i] = *(const short8v*)(Bp + ch * 128 + i * 8);

        if (ch) __syncthreads();

        {
            const int rt = sr >> 4, frr = sr & 15;
#pragma unroll
            for (int g = 0; g < 4; ++g) {
                float vv[8] = {a[g*2].x, a[g*2].y, a[g*2].z, a[g*2].w,
                               a[g*2+1].x, a[g*2+1].y, a[g*2+1].z, a[g*2+1].w};
                short8v hv, lv;
#pragma unroll
                for (int j = 0; j < 8; ++j) {
                    unsigned short h = f2bf(vv[j]);
                    hv[j] = (short)h;
                    lv[j] = (short)f2bf(vv[j] - bf2f(h));
                }
                *(short8v*)&AhL[rt][sks][g * 16 + frr][0] = hv;
                *(short8v*)&AlL[rt][sks][g * 16 + frr][0] = lv;
            }
        }
        if (qs) {
#pragma unroll
            for (int i = 0; i < 8; ++i) {
                const float arr[4] = {a[i].x, a[i].y, a[i].z, a[i].w};
#pragma unroll
                for (int j = 0; j < 4; ++j) {
                    int d = ch * 128 + sks * 32 + i * 4 + j;
                    float4 qw = *(const float4*)&wq[d * HD];
                    float4 kw = *(const float4*)&wk[d * HD];
                    qp[0] += arr[j] * qw.x; qp[1] += arr[j] * qw.y;
                    qp[2] += arr[j] * qw.z; qp[3] += arr[j] * qw.w;
                    kp[0] += arr[j] * kw.x; kp[1] += arr[j] * kw.y;
                    kp[2] += arr[j] * kw.z; kp[3] += arr[j] * kw.w;
                }
            }
        }
#pragma unroll
        for (int g = 0; g < 8; ++g) {
            int kk = bh2 + g * 8;
            int ksb = kk >> 5, fgb = (kk & 31) >> 3;
            *(short8v*)&BhL[ksb][bct][fgb * 16 + bfr][0] = b[g];
        }
        __syncthreads();

#pragma unroll
        for (int ksc = 0; ksc < 4; ++ksc) {
            short8v ah = *(const short8v*)&AhL[wave][ksc][lane][0];
            short8v al = *(const short8v*)&AlL[wave][ksc][lane][0];
#pragma unroll
            for (int c = 0; c < 8; ++c) {
                short8v bh = *(const short8v*)&BhL[ksc][c][lane][0];
                acc[c] = __builtin_amdgcn_mfma_f32_16x16x32_bf16(ah, bh, acc[c], 0, 0, 0);
                acc[c] = __builtin_amdgcn_mfma_f32_16x16x32_bf16(al, bh, acc[c], 0, 0, 0);
            }
        }
    }

    if (qs) {
#pragma unroll
        for (int off = 1; off < 4; off <<= 1) {
#pragma unroll
            for (int h = 0; h < 4; ++h) {
                qp[h] += __shfl_xor(qp[h], off, 64);
                kp[h] += __shfl_xor(kp[h], off, 64);
            }
        }
        if ((tid & 3) == 0) {
            int row = row0 + sr;
            if (row < M) {
                *(float4*)&qs[(size_t)row * HD] = make_float4(qp[0], qp[1], qp[2], qp[3]);
                *(float4*)&ks[(size_t)row * HD] = make_float4(kp[0], kp[1], kp[2], kp[3]);
            }
        }
    }

#pragma unroll
    for (int c = 0; c < 8; ++c) {
        float bv = bias ? bias[c * 16 + fr] : 0.f;
#pragma unroll
        for (int i = 0; i < 4; ++i) {
            int row = row0 + wave * 16 + fg * 4 + i;
            if (row < M) {
                float val = acc[c][i] + bv;
                if (Chf) Chf[(size_t)row * DD + c * 16 + fr] = __float2half(val);
                else     Cf [(size_t)row * DD + c * 16 + fr] = val;
            }
        }
    }
}

// ---------------------------------------------------------------------------
// CSR build: histogram + hierarchical 3-kernel scan + packed scatter.
// ---------------------------------------------------------------------------
__global__ __launch_bounds__(256) void csr_count(
    const int* __restrict__ dstv, int* __restrict__ deg, int E)
{
    int t = blockIdx.x * 256 + threadIdx.x;
    if (t < E) atomicAdd(&deg[dstv[t]], 1);
}

__global__ __launch_bounds__(SCAN_T) void scan_partial(
    const int* __restrict__ deg, int* __restrict__ blksum, int N)
{
    __shared__ int red[SCAN_T];
    int chunk = (N + SCAN_B - 1) / SCAN_B;
    int b0 = blockIdx.x * chunk;
    int e0 = b0 + chunk; if (e0 > N) e0 = N;
    int s = 0;
    for (int i = b0 + threadIdx.x; i < e0; i += SCAN_T) s += deg[i];
    red[threadIdx.x] = s;
    __syncthreads();
    for (int off = SCAN_T / 2; off > 0; off >>= 1) {
        if (threadIdx.x < off) red[threadIdx.x] += red[threadIdx.x + off];
        __syncthreads();
    }
    if (threadIdx.x == 0) blksum[blockIdx.x] = red[0];
}

__global__ __launch_bounds__(64) void scan_blk(
    const int* __restrict__ blksum, int* __restrict__ blkoff)
{
    if (threadIdx.x == 0) {
        int acc = 0;
        for (int i = 0; i < SCAN_B; ++i) { blkoff[i] = acc; acc += blksum[i]; }
        blkoff[SCAN_B] = acc;
    }
}

__global__ __launch_bounds__(SCAN_T) void scan_final(
    const int* __restrict__ deg, const int* __restrict__ blkoff,
    int* __restrict__ row_ptr, int N)
{
    __shared__ int tsum[SCAN_T];
    int tid = threadIdx.x;
    int chunk = (N + SCAN_B - 1) / SCAN_B;
    int b0 = blockIdx.x * chunk;
    int e0 = b0 + chunk; if (e0 > N) e0 = N;
    int tchunk = (chunk + SCAN_T - 1) / SCAN_T;
    int tb = b0 + tid * tchunk;
    int te = tb + tchunk; if (te > e0) te = e0;
    int s = 0;
    for (int i = tb; i < te; ++i) s += deg[i];
    tsum[tid] = s;
    __syncthreads();
    for (int off = 1; off < SCAN_T; off <<= 1) {
        int v = (tid >= off) ? tsum[tid - off] : 0;
        __syncthreads();
        tsum[tid] += v;
        __syncthreads();
    }
    int base = blkoff[blockIdx.x] + ((tid == 0) ? 0 : tsum[tid - 1]);
    for (int i = tb; i < te; ++i) { row_ptr[i] = base; base += deg[i]; }
    if (blockIdx.x == SCAN_B - 1 && tid == SCAN_T - 1) row_ptr[N] = blkoff[SCAN_B];
}

__global__ __launch_bounds__(256) void csr_scatter(
    const int* __restrict__ srcv, const int* __restrict__ dstv,
    const int* __restrict__ etype, const float* __restrict__ ew,
    const int* __restrict__ row_ptr, int* __restrict__ cursor,
    int4* __restrict__ c_pack, int E)
{
    int e = blockIdx.x * 256 + threadIdx.x;
    if (e >= E) return;
    int d = dstv[e];
    int p = row_ptr[d] + atomicAdd(&cursor[d], 1);
    c_pack[p] = make_int4(srcv[e], etype[e], __float_as_int(ew[e]), 0);
}

// ---------------------------------------------------------------------------
// Fused per-layer edge+softmax+aggregate+epilogue. One wave per dst node.
// Batch-4 edge loop; v gathered as fp16 (half the bytes of round 17).
// ---------------------------------------------------------------------------
__global__ __launch_bounds__(256) void fused_conv(
    const int* __restrict__ row_ptr, const int4* __restrict__ c_pack,
    const float* __restrict__ qs, const float* __restrict__ ks,
    const float* __restrict__ esum, const float* __restrict__ gate,
    const __half* __restrict__ v, const float* __restrict__ bias,
    float* __restrict__ out, int N, int do_elu)
{
    int gw = (blockIdx.x * 256 + threadIdx.x) >> 6;   // global wave id = node
    int lane = threadIdx.x & 63;
    if (gw >= N) return;
    const int n = gw;
    const int beg = row_ptr[n], end = row_ptr[n + 1];
    const int c0 = lane * 2;
    const int h = lane >> 4;
    const float L2E = 1.4426950408889634f;
    const float scL = 0.17677669529663687f * 1.4426950408889634f;  // (1/sqrt32)*log2e
    const float qh = qs[(size_t)n * HD + h];
    const float ghL = gate[h] * L2E;

    float num0 = 0.f, num1 = 0.f, den = 0.f;

    int j = beg;
    for (; j + 4 <= end; j += 4) {
        int4 p0 = c_pack[j];
        int4 p1 = c_pack[j + 1];
        int4 p2 = c_pack[j + 2];
        int4 p3 = c_pack[j + 3];
        float kh0 = ks[(size_t)p0.x * HD + h];
        float kh1 = ks[(size_t)p1.x * HD + h];
        float kh2 = ks[(size_t)p2.x * HD + h];
        float kh3 = ks[(size_t)p3.x * HD + h];
        float eh0 = esum[(size_t)p0.y * HD + h];
        float eh1 = esum[(size_t)p1.y * HD + h];
        float eh2 = esum[(size_t)p2.y * HD + h];
        float eh3 = esum[(size_t)p3.y * HD + h];
        float2 vv0 = __half22float2(*(const __half2*)&v[(size_t)p0.x * DD + c0]);
        float2 vv1 = __half22float2(*(const __half2*)&v[(size_t)p1.x * DD + c0]);
        float2 vv2 = __half22float2(*(const __half2*)&v[(size_t)p2.x * DD + c0]);
        float2 vv3 = __half22float2(*(const __half2*)&v[(size_t)p3.x * DD + c0]);
        float a0 = (qh + kh0 + eh0) * scL + ghL * __int_as_float(p0.z);
        float a1 = (qh + kh1 + eh1) * scL + ghL * __int_as_float(p1.z);
        float a2 = (qh + kh2 + eh2) * scL + ghL * __int_as_float(p2.z);
        float a3 = (qh + kh3 + eh3) * scL + ghL * __int_as_float(p3.z);
        a0 = a0 > 0.f ? a0 : 0.2f * a0;
        a1 = a1 > 0.f ? a1 : 0.2f * a1;
        a2 = a2 > 0.f ? a2 : 0.2f * a2;
        a3 = a3 > 0.f ? a3 : 0.2f * a3;
        float e0 = exp2f(a0), e1 = exp2f(a1);
        float e2 = exp2f(a2), e3 = exp2f(a3);
        den += (e0 + e1) + (e2 + e3);
        num0 = fmaf(e0, vv0.x, num0); num1 = fmaf(e0, vv0.y, num1);
        num0 = fmaf(e1, vv1.x, num0); num1 = fmaf(e1, vv1.y, num1);
        num0 = fmaf(e2, vv2.x, num0); num1 = fmaf(e2, vv2.y, num1);
        num0 = fmaf(e3, vv3.x, num0); num1 = fmaf(e3, vv3.y, num1);
    }
    for (; j < end; ++j) {
        int4 cur = c_pack[j];
        float kh = ks[(size_t)cur.x * HD + h];
        float eh = esum[(size_t)cur.y * HD + h];
        float2 vv = __half22float2(*(const __half2*)&v[(size_t)cur.x * DD + c0]);
        float a = (qh + kh + eh) * scL + ghL * __int_as_float(cur.z);
        a = a > 0.f ? a : 0.2f * a;
        float e = exp2f(a);
        den += e;
        num0 = fmaf(e, vv.x, num0);
        num1 = fmaf(e, vv.y, num1);
    }

    float inv = 1.f / (den + 1e-16f);
    float r0 = num0 * inv + bias[c0];
    float r1 = num1 * inv + bias[c0 + 1];
    if (do_elu) {
        r0 = r0 > 0.f ? r0 : expm1f(r0);
        r1 = r1 > 0.f ? r1 : expm1f(r1);
    }
    *(float2*)&out[(size_t)n * DD + c0] = make_float2(r0, r1);
}

// ---------------------------------------------------------------------------
extern "C" void kernel_launch(void* const* d_in, const int* in_sizes, int n_in,
                              void* d_out, int out_size, void* d_ws, size_t ws_size,
                              hipStream_t stream)
{
    const int*   entity = (const int*)d_in[0];
    const int*   eidx   = (const int*)d_in[1];
    const int*   etype  = (const int*)d_in[2];
    const float* ew     = (const float*)d_in[3];
    const float* ent    = (const float*)d_in[4];
    const float* pw     = (const float*)d_in[5];
    const float* pb     = (const float*)d_in[6];
    const float* rel    = (const float*)d_in[7];
    const float* Wq     = (const float*)d_in[8];
    const float* Wk     = (const float*)d_in[9];
    const float* Wv     = (const float*)d_in[10];
    const float* We     = (const float*)d_in[11];
    const float* gate   = (const float*)d_in[12];
    const float* cb     = (const float*)d_in[13];

    const int N = in_sizes[0];
    const int E = in_sizes[2];
    const int F = in_sizes[4] / N;     // 256
    const int R = in_sizes[7] / DD;    // 200

    const int* srcv = eidx;
    const int* dstv = eidx + E;

    float* ws = (float*)d_ws;
    size_t o = 0;
    float* xbuf    = ws + o; o += (size_t)N * DD;
    __half* vbuf   = (__half*)(ws + o); o += (size_t)N * DD / 2;   // fp16 v
    float* qs      = ws + o; o += (size_t)N * HD;
    float* ks      = ws + o; o += (size_t)N * HD;
    float* Wqh     = ws + o; o += 2 * DD * HD;
    float* Wkh     = ws + o; o += 2 * DD * HD;
    float* esum    = ws + o; o += (size_t)2 * R * HD;
    int*   deg     = (int*)(ws + o); o += N;
    int*   cursor  = (int*)(ws + o); o += N;
    int*   row_ptr = (int*)(ws + o); o += (size_t)N + 1;
    int*   blksum  = (int*)(ws + o); o += SCAN_B;
    int*   blkoff  = (int*)(ws + o); o += SCAN_B + 1;
    o = (o + 3) & ~(size_t)3;                       // 16B-align
    int4*  c_pack  = (int4*)(ws + o); o += (size_t)E * 4;
    unsigned short* btp = (unsigned short*)(ws + o); o += 128 * 256 / 2;
    unsigned short* btv = (unsigned short*)(ws + o); o += 2 * DD * DD / 2;

    prep_kernel<<<1, 256, 0, stream>>>(Wq, Wk, We, rel, Wqh, Wkh, esum, R);
    prep_bt<<<(128 * 256 + 2 * DD * DD + 255) / 256, 256, 0, stream>>>(
        pw, Wv, btp, btv);

    // CSR build (layer-independent, built once)
    hipMemsetAsync(deg, 0, (size_t)2 * N * sizeof(int), stream);  // deg + cursor
    csr_count<<<(E + 255) / 256, 256, 0, stream>>>(dstv, deg, E);
    scan_partial<<<SCAN_B, SCAN_T, 0, stream>>>(deg, blksum, N);
    scan_blk<<<1, 64, 0, stream>>>(blksum, blkoff);
    scan_final<<<SCAN_B, SCAN_T, 0, stream>>>(deg, blkoff, row_ptr, N);
    csr_scatter<<<(E + 255) / 256, 256, 0, stream>>>(
        srcv, dstv, etype, ew, row_ptr, cursor, c_pack, E);

    const int gblk = (N + 63) / 64;
    // x0 = ent_table[entity] @ proj_w + proj_b   (MFMA, K=256, fp32 out)
    gemm_mfma<<<gblk, 256, 0, stream>>>(
        ent, entity, btp, pb, nullptr, nullptr,
        xbuf, nullptr, nullptr, nullptr, N, F);

    const int fblk = (N + 3) / 4;     // one 64-lane wave per node
    for (int l = 0; l < 2; ++l) {
        gemm_mfma<<<gblk, 256, 0, stream>>>(
            xbuf, nullptr, btv + (size_t)l * DD * DD, nullptr,
            Wqh + l * DD * HD, Wkh + l * DD * HD,
            nullptr, vbuf, qs, ks, N, DD);
        fused_conv<<<fblk, 256, 0, stream>>>(
            row_ptr, c_pack, qs, ks, esum + (size_t)l * R * HD,
            gate + l * HD, vbuf, cb + l * DD,
            (l == 0) ? xbuf : (float*)d_out, N, (l == 0) ? 1 : 0);
    }
}